// Round 12
// baseline (953.599 us; speedup 1.0000x reference)
//
#include <hip/hip_runtime.h>

// ---------------- types / helpers ----------------
typedef float  f32x4  __attribute__((ext_vector_type(4)));
typedef float  f32x16 __attribute__((ext_vector_type(16)));
typedef __bf16 bf16x4 __attribute__((ext_vector_type(4)));
typedef __bf16 bf16x8 __attribute__((ext_vector_type(8)));

#define MFMA16(a,b,c) __builtin_amdgcn_mfma_f32_16x16x32_bf16((a),(b),(c),0,0,0)
#define MFMA32(a,b,c) __builtin_amdgcn_mfma_f32_32x32x16_bf16((a),(b),(c),0,0,0)

__device__ __forceinline__ void async_copy16(void* lds, const void* gmem) {
  __builtin_amdgcn_global_load_lds(
      (const __attribute__((address_space(1))) void*)gmem,
      (__attribute__((address_space(3))) void*)lds, 16, 0, 0);
}

template<int N> __device__ __forceinline__ void vmcnt_gate() {
  if constexpr (N == 8) asm volatile("s_waitcnt vmcnt(8)" ::: "memory");
  else if constexpr (N == 6) asm volatile("s_waitcnt vmcnt(6)" ::: "memory");
  else if constexpr (N == 4) asm volatile("s_waitcnt vmcnt(4)" ::: "memory");
  else if constexpr (N == 2) asm volatile("s_waitcnt vmcnt(2)" ::: "memory");
  else if constexpr (N == 0) asm volatile("s_waitcnt vmcnt(0)" ::: "memory");
  __builtin_amdgcn_sched_barrier(0);
}

// counted lgkm wait: drains all ds_reads OLDER than the N just issued (rule #18 fences)
#define LGKM(N) do { __builtin_amdgcn_sched_barrier(0); \
                     asm volatile("s_waitcnt lgkmcnt(" #N ")" ::: "memory"); \
                     __builtin_amdgcn_sched_barrier(0); } while (0)

#define BARRIER do { __builtin_amdgcn_sched_barrier(0); \
                     __builtin_amdgcn_s_barrier(); \
                     __builtin_amdgcn_sched_barrier(0); } while (0)

// ---------------- convert f32 -> bf16 ----------------
__global__ __launch_bounds__(256) void convert_kernel(const float* __restrict__ in,
                                                      __bf16* __restrict__ out, size_t n4) {
  size_t i = (size_t)blockIdx.x * 256 + threadIdx.x;
  if (i >= n4) return;
  f32x4 v = *(const f32x4*)(in + i * 4);
  bf16x4 o;
  #pragma unroll
  for (int j = 0; j < 4; ++j) o[j] = (__bf16)v[j];
  *(bf16x4*)(out + i * 4) = o;
}

// ---------------- transpose + convert: in f32 (R,C) -> out bf16 (C,R) ----------------
__global__ __launch_bounds__(256) void transpose_kernel(const float* __restrict__ in,
                                                        __bf16* __restrict__ out, int R, int C) {
  __shared__ float tile[32][33];
  int bx = blockIdx.x, by = blockIdx.y;
  int tx = threadIdx.x & 31, ty0 = threadIdx.x >> 5;
  #pragma unroll
  for (int i = 0; i < 4; ++i) {
    int r = by * 32 + ty0 + i * 8;
    tile[ty0 + i * 8][tx] = in[(size_t)r * C + bx * 32 + tx];
  }
  __syncthreads();
  #pragma unroll
  for (int i = 0; i < 4; ++i) {
    int c = bx * 32 + ty0 + i * 8;
    out[(size_t)c * R + by * 32 + tx] = (__bf16)tile[tx][ty0 + i * 8];
  }
}

// ---------------- shared staging (both GEMM variants) ----------------
template<bool REMAP>
__device__ __forceinline__ void stage_q(__bf16* region, int qrow, const __bf16* src,
                                        int K, int w, int l) {
  int s = qrow + w * 8 + (l >> 3);
  int gr = REMAP ? (((s >> 5) << 4) | (s & 15) | (((s >> 4) & 1) << 7)) : s;
  async_copy16(region + (size_t)(qrow + w * 8) * 64,
               src + (size_t)gr * K + (((l & 7) ^ (s & 7)) << 3));
}

// ---------------- 256x256 pipelined bf16 GEMM, 16x16x32 path (Q/K/V, FROZEN) ---------
// K-loop (race-proven R3 schedule) + MODE epilogues: 1=RoPE fused, 2=V permuted store.

template<bool LATE, bool EARLY, bool NEXT, int G2, int G3, bool BMAP>
__device__ __forceinline__ void tile_body(__bf16* smem,
                                          const __bf16* Apan, const __bf16* Bpan,
                                          int K, int tau, int wm, int wn,
                                          int lo, int hi, int w, int l,
                                          bf16x8 (&aA)[4], bf16x8 (&aB)[4],
                                          bf16x8 (&bA)[4], bf16x8 (&bB)[4],
                                          f32x4 (&acc)[8][4]) {
  const int buf = tau & 1;
  __bf16* Ab = smem + buf * 32768;
  __bf16* Bb = Ab + 16384;
  __bf16* An = smem + (buf ^ 1) * 32768;
  __bf16* Bn = An + 16384;

  // ---- block0
  #pragma unroll
  for (int t = 0; t < 4; ++t) {
    int ra = wm * 128 + 64 + t * 16 + lo;
    aB[t] = *(const bf16x8*)(Ab + (size_t)ra * 64 + ((hi ^ (ra & 7)) << 3));
  }
  if constexpr (LATE) {
    const __bf16* Ap1 = Apan + (size_t)(tau + 1) * 64;
    stage_q<false>(An, 64,  Ap1, K, w, l);
    stage_q<false>(An, 192, Ap1, K, w, l);
  }
  LGKM(4);
  __builtin_amdgcn_s_setprio(1);
  #pragma unroll
  for (int mt = 0; mt < 4; ++mt)
    #pragma unroll
    for (int nt = 0; nt < 4; ++nt)
      acc[mt][nt] = MFMA16(aA[mt], bA[nt], acc[mt][nt]);
  __builtin_amdgcn_s_setprio(0);
  BARRIER;

  // ---- block1
  #pragma unroll
  for (int t = 0; t < 4; ++t) {
    int ra = wm * 128 + t * 16 + lo;
    aA[t] = *(const bf16x8*)(Ab + (size_t)ra * 64 + (((4 + hi) ^ (ra & 7)) << 3));
  }
  #pragma unroll
  for (int t = 0; t < 4; ++t) {
    int rb = wn * 64 + t * 16 + lo;
    bB[t] = *(const bf16x8*)(Bb + (size_t)rb * 64 + (((4 + hi) ^ (rb & 7)) << 3));
  }
  LGKM(8);
  __builtin_amdgcn_s_setprio(1);
  #pragma unroll
  for (int mt = 0; mt < 4; ++mt)
    #pragma unroll
    for (int nt = 0; nt < 4; ++nt)
      acc[4 + mt][nt] = MFMA16(aB[mt], bA[nt], acc[4 + mt][nt]);
  __builtin_amdgcn_s_setprio(0);
  BARRIER;

  // ---- block2
  #pragma unroll
  for (int t = 0; t < 4; ++t) {
    int ra = wm * 128 + 64 + t * 16 + lo;
    aB[t] = *(const bf16x8*)(Ab + (size_t)ra * 64 + (((4 + hi) ^ (ra & 7)) << 3));
  }
  LGKM(4);
  __builtin_amdgcn_s_setprio(1);
  #pragma unroll
  for (int mt = 0; mt < 4; ++mt)
    #pragma unroll
    for (int nt = 0; nt < 4; ++nt)
      acc[mt][nt] = MFMA16(aA[mt], bB[nt], acc[mt][nt]);
  __builtin_amdgcn_s_setprio(0);
  if constexpr (G2 >= 0) vmcnt_gate<G2>();
  BARRIER;

  // ---- block3
  if constexpr (NEXT) {
    #pragma unroll
    for (int t = 0; t < 4; ++t) {
      int ra = wm * 128 + t * 16 + lo;
      aA[t] = *(const bf16x8*)(An + (size_t)ra * 64 + ((hi ^ (ra & 7)) << 3));
    }
    #pragma unroll
    for (int t = 0; t < 4; ++t) {
      int rb = wn * 64 + t * 16 + lo;
      bA[t] = *(const bf16x8*)(Bn + (size_t)rb * 64 + ((hi ^ (rb & 7)) << 3));
    }
  }
  if constexpr (EARLY) {
    const __bf16* Ap2 = Apan + (size_t)(tau + 2) * 64;
    const __bf16* Bp2 = Bpan + (size_t)(tau + 2) * 64;
    stage_q<false>(Ab, 0,   Ap2, K, w, l);
    stage_q<false>(Ab, 128, Ap2, K, w, l);
    stage_q<BMAP>(Bb, 0,   Bp2, K, w, l);
    stage_q<BMAP>(Bb, 64,  Bp2, K, w, l);
    stage_q<BMAP>(Bb, 128, Bp2, K, w, l);
    stage_q<BMAP>(Bb, 192, Bp2, K, w, l);
  }
  if constexpr (NEXT) LGKM(8); else LGKM(0);
  __builtin_amdgcn_s_setprio(1);
  #pragma unroll
  for (int mt = 0; mt < 4; ++mt)
    #pragma unroll
    for (int nt = 0; nt < 4; ++nt)
      acc[4 + mt][nt] = MFMA16(aB[mt], bB[nt], acc[4 + mt][nt]);
  __builtin_amdgcn_s_setprio(0);
  if constexpr (G3 >= 0) vmcnt_gate<G3>();
  BARRIER;
}

template <typename CT, int MODE>
__global__ __launch_bounds__(512, 2) void gemm256_kernel(const __bf16* __restrict__ A,
                                                         const __bf16* __restrict__ Bt,
                                                         CT* __restrict__ C, int M, int N, int K,
                                                         const float* __restrict__ cosT,
                                                         const float* __restrict__ sinT,
                                                         int Hh) {
  extern __shared__ __bf16 smem[];
  constexpr bool BMAP = (MODE == 1);

  const int gx = gridDim.x;
  const int nwg = gx * gridDim.y;
  const int wg = blockIdx.y * gx + blockIdx.x;
  const int qq = nwg >> 3;
  const int id2 = (wg & 7) * qq + (wg >> 3);
  const int m0 = (id2 / gx) * 256, n0 = (id2 % gx) * 256;

  const int tid = threadIdx.x;
  const int l = tid & 63, w = tid >> 6;
  const int lo = l & 15, hi = l >> 4;
  const int wm = w >> 2, wn = w & 3;

  const __bf16* Apan = A + (size_t)m0 * K;
  const __bf16* Bpan = Bt + (size_t)n0 * K;

  f32x4 acc[8][4] = {};
  bf16x8 aA[4], aB[4], bA[4], bB[4];

  stage_q<false>(smem,          0,   Apan, K, w, l);
  stage_q<false>(smem,          128, Apan, K, w, l);
  stage_q<BMAP>(smem + 16384,  0,   Bpan, K, w, l);
  stage_q<BMAP>(smem + 16384,  64,  Bpan, K, w, l);
  stage_q<BMAP>(smem + 16384,  128, Bpan, K, w, l);
  stage_q<BMAP>(smem + 16384,  192, Bpan, K, w, l);
  stage_q<false>(smem,          64,  Apan, K, w, l);
  stage_q<false>(smem,          192, Apan, K, w, l);
  stage_q<false>(smem + 32768,  0,   Apan + 64, K, w, l);
  stage_q<false>(smem + 32768,  128, Apan + 64, K, w, l);
  stage_q<BMAP>(smem + 49152,  0,   Bpan + 64, K, w, l);
  stage_q<BMAP>(smem + 49152,  64,  Bpan + 64, K, w, l);
  stage_q<BMAP>(smem + 49152,  128, Bpan + 64, K, w, l);
  stage_q<BMAP>(smem + 49152,  192, Bpan + 64, K, w, l);
  stage_q<false>(smem + 32768,  64,  Apan + 64, K, w, l);
  stage_q<false>(smem + 32768,  192, Apan + 64, K, w, l);
  vmcnt_gate<8>();
  BARRIER;

  #pragma unroll
  for (int t = 0; t < 4; ++t) {
    int ra = wm * 128 + t * 16 + lo;
    aA[t] = *(const bf16x8*)(smem + (size_t)ra * 64 + ((hi ^ (ra & 7)) << 3));
  }
  #pragma unroll
  for (int t = 0; t < 4; ++t) {
    int rb = wn * 64 + t * 16 + lo;
    bA[t] = *(const bf16x8*)(smem + 16384 + (size_t)rb * 64 + ((hi ^ (rb & 7)) << 3));
  }

  const int T = K >> 6;
  tile_body<false, true,  true,  2,  6, BMAP>(smem, Apan, Bpan, K, 0,     wm, wn, lo, hi, w, l, aA, aB, bA, bB, acc);
  for (int tau = 1; tau < T - 2; ++tau)
    tile_body<true, true,  true,  2,  6, BMAP>(smem, Apan, Bpan, K, tau,   wm, wn, lo, hi, w, l, aA, aB, bA, bB, acc);
  tile_body<true,  false, true,  2,  0, BMAP>(smem, Apan, Bpan, K, T - 2, wm, wn, lo, hi, w, l, aA, aB, bA, bB, acc);
  tile_body<false, false, false, -1, -1, BMAP>(smem, Apan, Bpan, K, T - 1, wm, wn, lo, hi, w, l, aA, aB, bA, bB, acc);

  if constexpr (MODE == 2) {
    const int kv = n0 >> 8;
    #pragma unroll
    for (int mt = 0; mt < 8; ++mt)
      #pragma unroll
      for (int nt = 0; nt < 4; ++nt) {
        int col = wn * 64 + nt * 16 + lo;
        #pragma unroll
        for (int r = 0; r < 4; ++r) {
          int row = m0 + wm * 128 + mt * 16 + 4 * hi + r;
          int bb = row >> 12, sdx = row & 4095;
          C[(((size_t)(bb * Hh + kv)) * 4096 + sdx) * 256 + col] = (CT)acc[mt][nt][r];
        }
      }
  } else {
    const int hq = n0 >> 8;
    #pragma unroll
    for (int mt = 0; mt < 8; ++mt)
      #pragma unroll
      for (int ntp = 0; ntp < 4; ntp += 2) {
        int d = (2 * wn + (ntp >> 1)) * 16 + lo;
        #pragma unroll
        for (int r = 0; r < 4; ++r) {
          int row = m0 + wm * 128 + mt * 16 + 4 * hi + r;
          int bb = row >> 12, sdx = row & 4095;
          float cc = cosT[(size_t)sdx * 128 + d];
          float ss = sinT[(size_t)sdx * 128 + d];
          float x1 = acc[mt][ntp][r], x2 = acc[mt][ntp + 1][r];
          size_t base = (((size_t)(bb * Hh + hq)) * 4096 + sdx) * 256;
          C[base + d]       = (CT)(x1 * cc - x2 * ss);
          C[base + d + 128] = (CT)(x1 * ss + x2 * cc);
        }
      }
  }
}

// ---------------- O-GEMM: 32x32x16 MFMA variant (R12 experiment) ----------------
// Same tile/schedule/staging/gates as the 16x16 path (read counts per block are
// IDENTICAL: 4/8/4/8 -> same LGKM/vmcnt proof). Only fragment addressing, MFMA shape,
// and the plain-f32 epilogue differ. Fragment layout: A/B per-lane row=lane&31,
// k=8*(lane>>5)+j (16x16x32 convention generalized); C/D col=lane&31,
// row=(reg&3)+8*(reg>>2)+4*(lane>>5) [HW-verified m74/m101].
// Per block: 4 a-frags (2 m-sub x 2 k-slice) x 2 b x 2 ks = 8 MFMA32 (vs 16 MFMA16).

template<bool LATE, bool EARLY, bool NEXT, int G2, int G3>
__device__ __forceinline__ void tile_body32(__bf16* smem,
                                            const __bf16* Apan, const __bf16* Bpan,
                                            int K, int tau, int wm, int wn,
                                            int lo32, int hi32, int w, int l,
                                            bf16x8 (&aA)[2][2], bf16x8 (&aB)[2][2],
                                            bf16x8 (&bA)[2][2], bf16x8 (&bB)[2][2],
                                            f32x16 (&acc)[8]) {
  const int buf = tau & 1;
  __bf16* Ab = smem + buf * 32768;
  __bf16* Bb = Ab + 16384;
  __bf16* An = smem + (buf ^ 1) * 32768;
  __bf16* Bn = An + 16384;

  // ---- block0: read aB = a(h1,k0); LATE; lgkm(4) drains R0; M0 = aA x bA (mh=0)
  #pragma unroll
  for (int mt2 = 0; mt2 < 2; ++mt2)
    #pragma unroll
    for (int ks = 0; ks < 2; ++ks) {
      int ra = wm * 128 + 64 + mt2 * 32 + lo32;
      int g = ks * 2 + hi32;
      aB[mt2][ks] = *(const bf16x8*)(Ab + (size_t)ra * 64 + ((g ^ (ra & 7)) << 3));
    }
  if constexpr (LATE) {
    const __bf16* Ap1 = Apan + (size_t)(tau + 1) * 64;
    stage_q<false>(An, 64,  Ap1, K, w, l);
    stage_q<false>(An, 192, Ap1, K, w, l);
  }
  LGKM(4);
  __builtin_amdgcn_s_setprio(1);
  #pragma unroll
  for (int mt2 = 0; mt2 < 2; ++mt2)
    #pragma unroll
    for (int nt = 0; nt < 2; ++nt)
      #pragma unroll
      for (int ks = 0; ks < 2; ++ks)
        acc[mt2 * 2 + nt] = MFMA32(aA[mt2][ks], bA[nt][ks], acc[mt2 * 2 + nt]);
  __builtin_amdgcn_s_setprio(0);
  BARRIER;

  // ---- block1: read aA = a(h0,k1) + bB = b(k1); lgkm(8) drains R1; M1 = aB x bA (mh=1)
  #pragma unroll
  for (int mt2 = 0; mt2 < 2; ++mt2)
    #pragma unroll
    for (int ks = 0; ks < 2; ++ks) {
      int ra = wm * 128 + mt2 * 32 + lo32;
      int g = (2 + ks) * 2 + hi32;
      aA[mt2][ks] = *(const bf16x8*)(Ab + (size_t)ra * 64 + ((g ^ (ra & 7)) << 3));
    }
  #pragma unroll
  for (int nt = 0; nt < 2; ++nt)
    #pragma unroll
    for (int ks = 0; ks < 2; ++ks) {
      int rb = wn * 64 + nt * 32 + lo32;
      int g = (2 + ks) * 2 + hi32;
      bB[nt][ks] = *(const bf16x8*)(Bb + (size_t)rb * 64 + ((g ^ (rb & 7)) << 3));
    }
  LGKM(8);
  __builtin_amdgcn_s_setprio(1);
  #pragma unroll
  for (int mt2 = 0; mt2 < 2; ++mt2)
    #pragma unroll
    for (int nt = 0; nt < 2; ++nt)
      #pragma unroll
      for (int ks = 0; ks < 2; ++ks)
        acc[4 + mt2 * 2 + nt] = MFMA32(aB[mt2][ks], bA[nt][ks], acc[4 + mt2 * 2 + nt]);
  __builtin_amdgcn_s_setprio(0);
  BARRIER;

  // ---- block2: read aB = a(h1,k1); lgkm(4) drains R2; M2 = aA x bB (mh=0); G2 gate
  #pragma unroll
  for (int mt2 = 0; mt2 < 2; ++mt2)
    #pragma unroll
    for (int ks = 0; ks < 2; ++ks) {
      int ra = wm * 128 + 64 + mt2 * 32 + lo32;
      int g = (2 + ks) * 2 + hi32;
      aB[mt2][ks] = *(const bf16x8*)(Ab + (size_t)ra * 64 + ((g ^ (ra & 7)) << 3));
    }
  LGKM(4);
  __builtin_amdgcn_s_setprio(1);
  #pragma unroll
  for (int mt2 = 0; mt2 < 2; ++mt2)
    #pragma unroll
    for (int nt = 0; nt < 2; ++nt)
      #pragma unroll
      for (int ks = 0; ks < 2; ++ks)
        acc[mt2 * 2 + nt] = MFMA32(aA[mt2][ks], bB[nt][ks], acc[mt2 * 2 + nt]);
  __builtin_amdgcn_s_setprio(0);
  if constexpr (G2 >= 0) vmcnt_gate<G2>();
  BARRIER;

  // ---- block3: read next aA,bA from nbuf; EARLY; lgkm(8|0); M3 = aB x bB (mh=1); G3
  if constexpr (NEXT) {
    #pragma unroll
    for (int mt2 = 0; mt2 < 2; ++mt2)
      #pragma unroll
      for (int ks = 0; ks < 2; ++ks) {
        int ra = wm * 128 + mt2 * 32 + lo32;
        int g = ks * 2 + hi32;
        aA[mt2][ks] = *(const bf16x8*)(An + (size_t)ra * 64 + ((g ^ (ra & 7)) << 3));
      }
    #pragma unroll
    for (int nt = 0; nt < 2; ++nt)
      #pragma unroll
      for (int ks = 0; ks < 2; ++ks) {
        int rb = wn * 64 + nt * 32 + lo32;
        int g = ks * 2 + hi32;
        bA[nt][ks] = *(const bf16x8*)(Bn + (size_t)rb * 64 + ((g ^ (rb & 7)) << 3));
      }
  }
  if constexpr (EARLY) {
    const __bf16* Ap2 = Apan + (size_t)(tau + 2) * 64;
    const __bf16* Bp2 = Bpan + (size_t)(tau + 2) * 64;
    stage_q<false>(Ab, 0,   Ap2, K, w, l);
    stage_q<false>(Ab, 128, Ap2, K, w, l);
    stage_q<false>(Bb, 0,   Bp2, K, w, l);
    stage_q<false>(Bb, 64,  Bp2, K, w, l);
    stage_q<false>(Bb, 128, Bp2, K, w, l);
    stage_q<false>(Bb, 192, Bp2, K, w, l);
  }
  if constexpr (NEXT) LGKM(8); else LGKM(0);
  __builtin_amdgcn_s_setprio(1);
  #pragma unroll
  for (int mt2 = 0; mt2 < 2; ++mt2)
    #pragma unroll
    for (int nt = 0; nt < 2; ++nt)
      #pragma unroll
      for (int ks = 0; ks < 2; ++ks)
        acc[4 + mt2 * 2 + nt] = MFMA32(aB[mt2][ks], bB[nt][ks], acc[4 + mt2 * 2 + nt]);
  __builtin_amdgcn_s_setprio(0);
  if constexpr (G3 >= 0) vmcnt_gate<G3>();
  BARRIER;
}

__global__ __launch_bounds__(512, 2) void gemm256o_kernel(const __bf16* __restrict__ A,
                                                          const __bf16* __restrict__ Bt,
                                                          float* __restrict__ C,
                                                          int M, int N, int K) {
  extern __shared__ __bf16 smem[];

  const int gx = gridDim.x;
  const int nwg = gx * gridDim.y;
  const int wg = blockIdx.y * gx + blockIdx.x;
  const int qq = nwg >> 3;
  const int id2 = (wg & 7) * qq + (wg >> 3);
  const int m0 = (id2 / gx) * 256, n0 = (id2 % gx) * 256;

  const int tid = threadIdx.x;
  const int l = tid & 63, w = tid >> 6;
  const int lo32 = l & 31, hi32 = l >> 5;
  const int wm = w >> 2, wn = w & 3;

  const __bf16* Apan = A + (size_t)m0 * K;
  const __bf16* Bpan = Bt + (size_t)n0 * K;

  f32x16 acc[8] = {};
  bf16x8 aA[2][2], aB[2][2], bA[2][2], bB[2][2];

  stage_q<false>(smem,          0,   Apan, K, w, l);
  stage_q<false>(smem,          128, Apan, K, w, l);
  stage_q<false>(smem + 16384,  0,   Bpan, K, w, l);
  stage_q<false>(smem + 16384,  64,  Bpan, K, w, l);
  stage_q<false>(smem + 16384,  128, Bpan, K, w, l);
  stage_q<false>(smem + 16384,  192, Bpan, K, w, l);
  stage_q<false>(smem,          64,  Apan, K, w, l);
  stage_q<false>(smem,          192, Apan, K, w, l);
  stage_q<false>(smem + 32768,  0,   Apan + 64, K, w, l);
  stage_q<false>(smem + 32768,  128, Apan + 64, K, w, l);
  stage_q<false>(smem + 49152,  0,   Bpan + 64, K, w, l);
  stage_q<false>(smem + 49152,  64,  Bpan + 64, K, w, l);
  stage_q<false>(smem + 49152,  128, Bpan + 64, K, w, l);
  stage_q<false>(smem + 49152,  192, Bpan + 64, K, w, l);
  stage_q<false>(smem + 32768,  64,  Apan + 64, K, w, l);
  stage_q<false>(smem + 32768,  192, Apan + 64, K, w, l);
  vmcnt_gate<8>();
  BARRIER;

  // R0: aA = a(h0,k0), bA = b(k0)
  #pragma unroll
  for (int mt2 = 0; mt2 < 2; ++mt2)
    #pragma unroll
    for (int ks = 0; ks < 2; ++ks) {
      int ra = wm * 128 + mt2 * 32 + lo32;
      int g = ks * 2 + hi32;
      aA[mt2][ks] = *(const bf16x8*)(smem + (size_t)ra * 64 + ((g ^ (ra & 7)) << 3));
    }
  #pragma unroll
  for (int nt = 0; nt < 2; ++nt)
    #pragma unroll
    for (int ks = 0; ks < 2; ++ks) {
      int rb = wn * 64 + nt * 32 + lo32;
      int g = ks * 2 + hi32;
      bA[nt][ks] = *(const bf16x8*)(smem + 16384 + (size_t)rb * 64 + ((g ^ (rb & 7)) << 3));
    }

  const int T = K >> 6;
  tile_body32<false, true,  true,  2,  6>(smem, Apan, Bpan, K, 0,     wm, wn, lo32, hi32, w, l, aA, aB, bA, bB, acc);
  for (int tau = 1; tau < T - 2; ++tau)
    tile_body32<true, true,  true,  2,  6>(smem, Apan, Bpan, K, tau,   wm, wn, lo32, hi32, w, l, aA, aB, bA, bB, acc);
  tile_body32<true,  false, true,  2,  0>(smem, Apan, Bpan, K, T - 2, wm, wn, lo32, hi32, w, l, aA, aB, bA, bB, acc);
  tile_body32<false, false, false, -1, -1>(smem, Apan, Bpan, K, T - 1, wm, wn, lo32, hi32, w, l, aA, aB, bA, bB, acc);

  // epilogue: C/D layout col=lane&31, row=(r&3)+8*(r>>2)+4*(lane>>5)
  #pragma unroll
  for (int ct = 0; ct < 8; ++ct) {
    int mt = ct >> 1, nt = ct & 1;
    int col = n0 + wn * 64 + nt * 32 + lo32;
    #pragma unroll
    for (int r = 0; r < 16; ++r) {
      int row = m0 + wm * 128 + mt * 32 + (r & 3) + 8 * (r >> 2) + 4 * hi32;
      C[(size_t)row * N + col] = acc[ct][r];
    }
  }
}

// ---------------- feature map ----------------
__global__ __launch_bounds__(256) void fm_kernel(const __bf16* __restrict__ rope,
                                                 const float* __restrict__ fm,
                                                 __bf16* __restrict__ out, int srcH, float scale) {
  __shared__ __bf16 fmT[64][256];
  int bh = blockIdx.y;
  int h = bh & 15, b = bh >> 4;
  int s0 = blockIdx.x * 128;
  int tid = threadIdx.x, lane = tid & 63, wid = tid >> 6, hi = lane >> 4, lo = lane & 15;

  const float* fmh = fm + (size_t)h * 256 * 64;
  for (int i = tid; i < 256 * 64; i += 256) {
    int d = i >> 6, f = i & 63;
    fmT[f][(((d >> 3) ^ (f & 7)) << 3) | (d & 7)] = (__bf16)fmh[i];
  }
  __syncthreads();

  int srch = (srcH == 16) ? h : (h >> 1);
  const __bf16* abase = rope + ((size_t)(b * srcH + srch) * 4096 + s0 + 32 * wid) * 256;
  f32x4 acc[2][4] = {};
  for (int kk = 0; kk < 256; kk += 32) {
    bf16x8 a[2], bf[4];
    #pragma unroll
    for (int mt = 0; mt < 2; ++mt)
      a[mt] = *(const bf16x8*)(abase + (size_t)(16 * mt + lo) * 256 + kk + 8 * hi);
    const int G = (kk >> 3) + hi;
    #pragma unroll
    for (int nt = 0; nt < 4; ++nt) {
      int f = 16 * nt + lo;
      bf[nt] = *(const bf16x8*)&fmT[f][(G ^ (f & 7)) << 3];
    }
    #pragma unroll
    for (int mt = 0; mt < 2; ++mt)
      #pragma unroll
      for (int nt = 0; nt < 4; ++nt)
        acc[mt][nt] = MFMA16(a[mt], bf[nt], acc[mt][nt]);
  }

  size_t obase = ((size_t)(b * 16 + h) * 4096 + s0 + 32 * wid);
  #pragma unroll
  for (int mt = 0; mt < 2; ++mt) {
    #pragma unroll
    for (int r = 0; r < 4; ++r) {
      float z0 = acc[mt][0][r], z1 = acc[mt][1][r], z2 = acc[mt][2][r], z3 = acc[mt][3][r];
      float mx = fmaxf(fmaxf(z0, z1), fmaxf(z2, z3));
      float mn = fminf(fminf(z0, z1), fminf(z2, z3));
      #pragma unroll
      for (int off = 1; off < 16; off <<= 1) {
        mx = fmaxf(mx, __shfl_xor(mx, off));
        mn = fminf(mn, __shfl_xor(mn, off));
      }
      float ep0 = __expf(z0 - mx), ep1 = __expf(z1 - mx), ep2 = __expf(z2 - mx), ep3 = __expf(z3 - mx);
      float en0 = __expf(mn - z0), en1 = __expf(mn - z1), en2 = __expf(mn - z2), en3 = __expf(mn - z3);
      float sp = ep0 + ep1 + ep2 + ep3, sn = en0 + en1 + en2 + en3;
      #pragma unroll
      for (int off = 1; off < 16; off <<= 1) {
        sp += __shfl_xor(sp, off);
        sn += __shfl_xor(sn, off);
      }
      float rp = scale / sp, rn = scale / sn;
      int row = 16 * mt + 4 * hi + r;
      __bf16* op = out + (obase + row) * 128;
      op[0  + lo] = (__bf16)(ep0 * rp);  op[16 + lo] = (__bf16)(ep1 * rp);
      op[32 + lo] = (__bf16)(ep2 * rp);  op[48 + lo] = (__bf16)(ep3 * rp);
      op[64 + lo] = (__bf16)(en0 * rn);  op[80 + lo] = (__bf16)(en1 * rn);
      op[96 + lo] = (__bf16)(en2 * rn);  op[112 + lo] = (__bf16)(en3 * rn);
    }
  }
}

// ---------------- chunked linear attention (R8: software-pipelined) ----------------
__global__ __launch_bounds__(256) void attn_kernel(const __bf16* __restrict__ qf,
                                                   const __bf16* __restrict__ kf,
                                                   const __bf16* __restrict__ vp,
                                                   __bf16* __restrict__ o) {
  __shared__ __bf16 k_s[2][64][128];
  __shared__ __bf16 vT_s[2][32][64];
  __shared__ __bf16 sc_s[64][64];
  __shared__ __bf16 STb[32][128];

  int bid = blockIdx.x;
  int g   = ((bid >> 6) << 3) | (bid & 7);
  int dvb = (bid >> 3) & 7;
  int h = g & 15, b = g >> 4;
  int dv0 = dvb * 32;
  int tid = threadIdx.x, lane = tid & 63, wid = tid >> 6, hi = lane >> 4, lo = lane & 15;

  const __bf16* qh = qf + ((size_t)(b * 16 + h)) * 4096 * 128;
  const __bf16* kh = kf + ((size_t)(b * 16 + h)) * 4096 * 128;
  const __bf16* vh = vp + ((size_t)(b * 8 + (h >> 1))) * 4096 * 256 + dv0;
  __bf16* oh = o + ((size_t)b * 4096) * 4096 + h * 256 + dv0;

  {
    unsigned int* z = (unsigned int*)&STb[0][0];
    for (int i = tid; i < 2048; i += 256) z[i] = 0u;
  }
  f32x4 st[2][2] = {};

  const int vc = tid >> 2, vd8 = (tid & 3) * 8;
  bf16x8 aqN[4], aqC[4], vvN;

  #pragma unroll
  for (int i = 0; i < 4; ++i) {
    int rb = (wid * 4 + i) * 4;
    int r = rb + (lane >> 4);
    int Glog = (lane & 15) ^ (r & 7);
    async_copy16(&k_s[0][rb][0], kh + (size_t)r * 128 + Glog * 8);
  }
  __builtin_amdgcn_sched_barrier(0);
  vvN = *(const bf16x8*)(vh + (size_t)vc * 256 + vd8);
  __builtin_amdgcn_sched_barrier(0);
  #pragma unroll
  for (int kq = 0; kq < 4; ++kq)
    aqN[kq] = *(const bf16x8*)(qh + (size_t)(16 * wid + lo) * 128 + 32 * kq + 8 * hi);
  __builtin_amdgcn_sched_barrier(0);
  #pragma unroll
  for (int j = 0; j < 8; ++j) {
    int dv = vd8 + j;
    vT_s[0][dv][(((vc >> 3) ^ (dv & 7)) << 3) | (vc & 7)] = vvN[j];
  }
  LGKM(0);
  BARRIER;

  for (int n = 0; n < 64; ++n) {
    const int buf = n & 1;
    const int s0 = n * 64;

    #pragma unroll
    for (int kq = 0; kq < 4; ++kq) aqC[kq] = aqN[kq];

    if (n < 63) {
      const int s1 = s0 + 64;
      #pragma unroll
      for (int i = 0; i < 4; ++i) {
        int rb = (wid * 4 + i) * 4;
        int r = rb + (lane >> 4);
        int Glog = (lane & 15) ^ (r & 7);
        async_copy16(&k_s[buf ^ 1][rb][0], kh + (size_t)(s1 + r) * 128 + Glog * 8);
      }
      __builtin_amdgcn_sched_barrier(0);
      vvN = *(const bf16x8*)(vh + (size_t)(s1 + vc) * 256 + vd8);
      __builtin_amdgcn_sched_barrier(0);
      #pragma unroll
      for (int kq = 0; kq < 4; ++kq)
        aqN[kq] = *(const bf16x8*)(qh + (size_t)(s1 + 16 * wid + lo) * 128 + 32 * kq + 8 * hi);
      __builtin_amdgcn_sched_barrier(0);
    }

    f32x4 acc_o[2] = {}, sacc[4] = {};
    #pragma unroll
    for (int nt = 0; nt < 2; ++nt)
      #pragma unroll
      for (int kq = 0; kq < 4; ++kq) {
        int rr = 16 * nt + lo, G = 4 * kq + hi;
        bf16x8 bf = *(const bf16x8*)&STb[rr][(G ^ (rr & 7)) << 3];
        acc_o[nt] = MFMA16(aqC[kq], bf, acc_o[nt]);
      }
    #pragma unroll
    for (int nt = 0; nt < 4; ++nt)
      #pragma unroll
      for (int kq = 0; kq < 4; ++kq) {
        int rr = 16 * nt + lo, G = 4 * kq + hi;
        bf16x8 bf = *(const bf16x8*)&k_s[buf][rr][(G ^ (rr & 7)) << 3];
        sacc[nt] = MFMA16(aqC[kq], bf, sacc[nt]);
      }
    #pragma unroll
    for (int nt = 0; nt < 4; ++nt)
      #pragma unroll
      for (int r = 0; r < 4; ++r) {
        int c = 16 * wid + 4 * hi + r;
        int cp = 16 * nt + lo;
        float v = (cp <= c) ? sacc[nt][r] : 0.0f;
        sc_s[c][(((cp >> 3) ^ (c & 7)) << 3) | (cp & 7)] = (__bf16)v;
      }
    asm volatile("" ::: "memory");
    #pragma unroll
    for (int nt = 0; nt < 2; ++nt)
      #pragma unroll
      for (int kq = 0; kq < 2; ++kq) {
        int rA = 16 * wid + lo, GA = 4 * kq + hi;
        bf16x8 af = *(const bf16x8*)&sc_s[rA][(GA ^ (rA & 7)) << 3];
        int rB = 16 * nt + lo;
        bf16x8 bf = *(const bf16x8*)&vT_s[buf][rB][(GA ^ (rB & 7)) << 3];
        acc_o[nt] = MFMA16(af, bf, acc_o[nt]);
      }
    #pragma unroll
    for (int nt = 0; nt < 2; ++nt)
      #pragma unroll
      for (int r = 0; r < 4; ++r) {
        int c = 16 * wid + 4 * hi + r;
        oh[(size_t)(s0 + c) * 4096 + 16 * nt + lo] = (__bf16)acc_o[nt][r];
      }

    if (n == 63) break;

    BARRIER;

    bf16x8 bu[2][2];
    #pragma unroll
    for (int q = 0; q < 2; ++q) {
      int dk = 16 * (2 * wid + q) + lo;
      #pragma unroll
      for (int kq = 0; kq < 2; ++kq) {
        bf16x8 tmp;
        #pragma unroll
        for (int j = 0; j < 8; ++j) {
          int c = 32 * kq + 8 * hi + j;
          tmp[j] = k_s[buf][c][(((dk >> 3) ^ (c & 7)) << 3) | (dk & 7)];
        }
        bu[q][kq] = tmp;
      }
    }
    #pragma unroll
    for (int mt = 0; mt < 2; ++mt)
      #pragma unroll
      for (int kq = 0; kq < 2; ++kq) {
        int rA = 16 * mt + lo, GA = 4 * kq + hi;
        bf16x8 av = *(const bf16x8*)&vT_s[buf][rA][(GA ^ (rA & 7)) << 3];
        #pragma unroll
        for (int q = 0; q < 2; ++q)
          st[mt][q] = MFMA16(av, bu[q][kq], st[mt][q]);
      }
    #pragma unroll
    for (int mt = 0; mt < 2; ++mt)
      #pragma unroll
      for (int q = 0; q < 2; ++q) {
        int dk = 16 * (2 * wid + q) + lo;
        #pragma unroll
        for (int r = 0; r < 4; ++r) {
          int dvr = 16 * mt + 4 * hi + r;
          STb[dvr][(((dk >> 3) ^ (dvr & 7)) << 3) | (dk & 7)] = (__bf16)st[mt][q][r];
        }
      }
    #pragma unroll
    for (int j = 0; j < 8; ++j) {
      int dv = vd8 + j;
      vT_s[buf ^ 1][dv][(((vc >> 3) ^ (dv & 7)) << 3) | (vc & 7)] = vvN[j];
    }
    LGKM(0);
    BARRIER;
  }
}

// ---------------- launch ----------------
extern "C" void kernel_launch(void* const* d_in, const int* in_sizes, int n_in,
                              void* d_out, int out_size, void* d_ws, size_t ws_size,
                              hipStream_t stream) {
  (void)in_sizes; (void)n_in; (void)out_size; (void)ws_size;
  const float* hs   = (const float*)d_in[0];
  const float* cosT = (const float*)d_in[1];
  const float* sinT = (const float*)d_in[2];
  const float* Wq   = (const float*)d_in[3];
  const float* Wk   = (const float*)d_in[4];
  const float* Wv   = (const float*)d_in[5];
  const float* Wo   = (const float*)d_in[6];
  const float* fmq  = (const float*)d_in[7];
  const float* fmk  = (const float*)d_in[8];
  float* out = (float*)d_out;
  char* ws = (char*)d_ws;

  hipFuncSetAttribute((const void*)gemm256o_kernel,
                      hipFuncAttributeMaxDynamicSharedMemorySize, 131072);
  hipFuncSetAttribute((const void*)gemm256_kernel<__bf16, 1>,
                      hipFuncAttributeMaxDynamicSharedMemorySize, 131072);
  hipFuncSetAttribute((const void*)gemm256_kernel<__bf16, 2>,
                      hipFuncAttributeMaxDynamicSharedMemorySize, 131072);

  const size_t MB = 1024ull * 1024ull;
  __bf16* Xb   = (__bf16*)(ws + 0);
  __bf16* qfb  = (__bf16*)(ws + 0);
  __bf16* kfb  = (__bf16*)(ws + 34 * MB);
  __bf16* Wqt  = (__bf16*)(ws + 70 * MB);
  __bf16* ob   = (__bf16*)(ws + 70 * MB);
  __bf16* Wkt  = (__bf16*)(ws + 104 * MB);
  __bf16* Wvt  = (__bf16*)(ws + 119 * MB);
  __bf16* Wot  = (__bf16*)(ws + 140 * MB);
  __bf16* ropq = (__bf16*)(ws + 170 * MB);
  __bf16* ropk = (__bf16*)(ws + 238 * MB);
  __bf16* vpb  = (__bf16*)(ws + 272 * MB);

  convert_kernel<<<28672, 256, 0, stream>>>(hs, Xb, (size_t)8192 * 3584 / 4);
  transpose_kernel<<<dim3(128, 112), 256, 0, stream>>>(Wq, Wqt, 3584, 4096);
  transpose_kernel<<<dim3(64, 112),  256, 0, stream>>>(Wk, Wkt, 3584, 2048);
  transpose_kernel<<<dim3(64, 112),  256, 0, stream>>>(Wv, Wvt, 3584, 2048);
  transpose_kernel<<<dim3(112, 128), 256, 0, stream>>>(Wo, Wot, 4096, 3584);

  gemm256_kernel<__bf16, 1><<<dim3(16, 32), 512, 131072, stream>>>(
      Xb, Wqt, ropq, 8192, 4096, 3584, cosT, sinT, 16);
  gemm256_kernel<__bf16, 1><<<dim3(8, 32),  512, 131072, stream>>>(
      Xb, Wkt, ropk, 8192, 2048, 3584, cosT, sinT, 8);
  gemm256_kernel<__bf16, 2><<<dim3(8, 32),  512, 131072, stream>>>(
      Xb, Wvt, vpb, 8192, 2048, 3584, nullptr, nullptr, 8);

  fm_kernel<<<dim3(32, 32), 256, 0, stream>>>(ropq, fmq, qfb, 16, 0.08838834764831845f);
  fm_kernel<<<dim3(32, 32), 256, 0, stream>>>(ropk, fmk, kfb, 8, 1.0f);

  attn_kernel<<<256, 256, 0, stream>>>(qfb, kfb, vpb, ob);

  gemm256o_kernel<<<dim3(14, 32), 512, 131072, stream>>>(
      ob, Wot, out, 8192, 3584, 4096);
}

// Round 13
// 930.159 us; speedup vs baseline: 1.0252x; 1.0252x over previous
//
#include <hip/hip_runtime.h>

// ---------------- types / helpers ----------------
typedef float  f32x4  __attribute__((ext_vector_type(4)));
typedef __bf16 bf16x4 __attribute__((ext_vector_type(4)));
typedef __bf16 bf16x8 __attribute__((ext_vector_type(8)));

#define MFMA16(a,b,c) __builtin_amdgcn_mfma_f32_16x16x32_bf16((a),(b),(c),0,0,0)

__device__ __forceinline__ void async_copy16(void* lds, const void* gmem) {
  __builtin_amdgcn_global_load_lds(
      (const __attribute__((address_space(1))) void*)gmem,
      (__attribute__((address_space(3))) void*)lds, 16, 0, 0);
}

template<int N> __device__ __forceinline__ void vmcnt_gate() {
  if constexpr (N == 8) asm volatile("s_waitcnt vmcnt(8)" ::: "memory");
  else if constexpr (N == 6) asm volatile("s_waitcnt vmcnt(6)" ::: "memory");
  else if constexpr (N == 4) asm volatile("s_waitcnt vmcnt(4)" ::: "memory");
  else if constexpr (N == 2) asm volatile("s_waitcnt vmcnt(2)" ::: "memory");
  else if constexpr (N == 0) asm volatile("s_waitcnt vmcnt(0)" ::: "memory");
  __builtin_amdgcn_sched_barrier(0);
}

// counted lgkm wait: drains all ds_reads OLDER than the N just issued (rule #18 fences)
#define LGKM(N) do { __builtin_amdgcn_sched_barrier(0); \
                     asm volatile("s_waitcnt lgkmcnt(" #N ")" ::: "memory"); \
                     __builtin_amdgcn_sched_barrier(0); } while (0)

#define BARRIER do { __builtin_amdgcn_sched_barrier(0); \
                     __builtin_amdgcn_s_barrier(); \
                     __builtin_amdgcn_sched_barrier(0); } while (0)

// ---------------- convert f32 -> bf16 ----------------
__global__ __launch_bounds__(256) void convert_kernel(const float* __restrict__ in,
                                                      __bf16* __restrict__ out, size_t n4) {
  size_t i = (size_t)blockIdx.x * 256 + threadIdx.x;
  if (i >= n4) return;
  f32x4 v = *(const f32x4*)(in + i * 4);
  bf16x4 o;
  #pragma unroll
  for (int j = 0; j < 4; ++j) o[j] = (__bf16)v[j];
  *(bf16x4*)(out + i * 4) = o;
}

// ---------------- transpose + convert: in f32 (R,C) -> out bf16 (C,R) ----------------
__global__ __launch_bounds__(256) void transpose_kernel(const float* __restrict__ in,
                                                        __bf16* __restrict__ out, int R, int C) {
  __shared__ float tile[32][33];
  int bx = blockIdx.x, by = blockIdx.y;
  int tx = threadIdx.x & 31, ty0 = threadIdx.x >> 5;
  #pragma unroll
  for (int i = 0; i < 4; ++i) {
    int r = by * 32 + ty0 + i * 8;
    tile[ty0 + i * 8][tx] = in[(size_t)r * C + bx * 32 + tx];
  }
  __syncthreads();
  #pragma unroll
  for (int i = 0; i < 4; ++i) {
    int c = bx * 32 + ty0 + i * 8;
    out[(size_t)c * R + by * 32 + tx] = (__bf16)tile[tx][ty0 + i * 8];
  }
}

// ---------------- 256x256 pipelined bf16 GEMM (FINAL: R5 schedule, 232us, 45% MfmaUtil) --
// K-loop (race-proven R3 schedule) + MODE epilogues: 0=plain, 1=RoPE fused (B colmap
// permute -> intra-thread butterfly), 2=V permuted store.
// Session-bracketed design space (all measured):
//  - schedules: R1 shallow / R3 counted-lgkm / R4 m201-style 8-barrier / R6 2-block
//    -> basin at 40-46% MfmaUtil; R3 best.
//  - tiles: 256^2 uniquely L2-viable (128^2: FETCH 264->918MB, regressed).
//  - MFMA shape: 32x32x16 correct but 4-way LDS-bank-conflicted under this swizzle
//    (2.2e7 conflicts = +31us on O-GEMM; 4-way is the floor for 32-lane column reads
//    in 128B rows) -> 16x16x32 is the right shape for this layout.
//  - swizzle discipline: XOR group' = g ^ (row&7) gives 2 lanes/bank-class for
//    16-row fragment reads = free (0 conflicts measured).

template<bool REMAP>
__device__ __forceinline__ void stage_q(__bf16* region, int qrow, const __bf16* src,
                                        int K, int w, int l) {
  int s = qrow + w * 8 + (l >> 3);
  int gr = REMAP ? (((s >> 5) << 4) | (s & 15) | (((s >> 4) & 1) << 7)) : s;
  async_copy16(region + (size_t)(qrow + w * 8) * 64,
               src + (size_t)gr * K + (((l & 7) ^ (s & 7)) << 3));
}

template<bool LATE, bool EARLY, bool NEXT, int G2, int G3, bool BMAP>
__device__ __forceinline__ void tile_body(__bf16* smem,
                                          const __bf16* Apan, const __bf16* Bpan,
                                          int K, int tau, int wm, int wn,
                                          int lo, int hi, int w, int l,
                                          bf16x8 (&aA)[4], bf16x8 (&aB)[4],
                                          bf16x8 (&bA)[4], bf16x8 (&bB)[4],
                                          f32x4 (&acc)[8][4]) {
  const int buf = tau & 1;
  __bf16* Ab = smem + buf * 32768;
  __bf16* Bb = Ab + 16384;
  __bf16* An = smem + (buf ^ 1) * 32768;
  __bf16* Bn = An + 16384;

  // ---- block0: R1 = aB <- a(h1,k0)[buf]; S0 = LATE; lgkm(4) drains R0; M0 = aA*bA
  #pragma unroll
  for (int t = 0; t < 4; ++t) {
    int ra = wm * 128 + 64 + t * 16 + lo;
    aB[t] = *(const bf16x8*)(Ab + (size_t)ra * 64 + ((hi ^ (ra & 7)) << 3));
  }
  if constexpr (LATE) {
    const __bf16* Ap1 = Apan + (size_t)(tau + 1) * 64;
    stage_q<false>(An, 64,  Ap1, K, w, l);   // A q1
    stage_q<false>(An, 192, Ap1, K, w, l);   // A q3
  }
  LGKM(4);
  __builtin_amdgcn_s_setprio(1);
  #pragma unroll
  for (int mt = 0; mt < 4; ++mt)
    #pragma unroll
    for (int nt = 0; nt < 4; ++nt)
      acc[mt][nt] = MFMA16(aA[mt], bA[nt], acc[mt][nt]);
  __builtin_amdgcn_s_setprio(0);
  BARRIER;

  // ---- block1: R2 = aA <- a(h0,k1), bB <- b(k1) [buf]; lgkm(8) drains R1; M1 = aB*bA
  #pragma unroll
  for (int t = 0; t < 4; ++t) {
    int ra = wm * 128 + t * 16 + lo;
    aA[t] = *(const bf16x8*)(Ab + (size_t)ra * 64 + (((4 + hi) ^ (ra & 7)) << 3));
  }
  #pragma unroll
  for (int t = 0; t < 4; ++t) {
    int rb = wn * 64 + t * 16 + lo;
    bB[t] = *(const bf16x8*)(Bb + (size_t)rb * 64 + (((4 + hi) ^ (rb & 7)) << 3));
  }
  LGKM(8);
  __builtin_amdgcn_s_setprio(1);
  #pragma unroll
  for (int mt = 0; mt < 4; ++mt)
    #pragma unroll
    for (int nt = 0; nt < 4; ++nt)
      acc[4 + mt][nt] = MFMA16(aB[mt], bA[nt], acc[4 + mt][nt]);
  __builtin_amdgcn_s_setprio(0);
  BARRIER;

  // ---- block2: R3 = aB <- a(h1,k1)[buf]; lgkm(4) drains R2; M2 = aA*bB;
  //      G2 gate BEFORE bar2 (cross-wave: EARLY(tau+1) landed for everyone)
  #pragma unroll
  for (int t = 0; t < 4; ++t) {
    int ra = wm * 128 + 64 + t * 16 + lo;
    aB[t] = *(const bf16x8*)(Ab + (size_t)ra * 64 + (((4 + hi) ^ (ra & 7)) << 3));
  }
  LGKM(4);
  __builtin_amdgcn_s_setprio(1);
  #pragma unroll
  for (int mt = 0; mt < 4; ++mt)
    #pragma unroll
    for (int nt = 0; nt < 4; ++nt)
      acc[mt][nt] = MFMA16(aA[mt], bB[nt], acc[mt][nt]);
  __builtin_amdgcn_s_setprio(0);
  if constexpr (G2 >= 0) vmcnt_gate<G2>();
  BARRIER;

  // ---- block3: R0' = aA <- a(h0,k0), bA <- b(k0) [nbuf] (NEXT); S3 = EARLY(tau+2 -> buf);
  //      lgkm(8|0) drains R3; M3 = aB*bB; G3 gate BEFORE bar3 (LATE landed for everyone)
  if constexpr (NEXT) {
    #pragma unroll
    for (int t = 0; t < 4; ++t) {
      int ra = wm * 128 + t * 16 + lo;
      aA[t] = *(const bf16x8*)(An + (size_t)ra * 64 + ((hi ^ (ra & 7)) << 3));
    }
    #pragma unroll
    for (int t = 0; t < 4; ++t) {
      int rb = wn * 64 + t * 16 + lo;
      bA[t] = *(const bf16x8*)(Bn + (size_t)rb * 64 + ((hi ^ (rb & 7)) << 3));
    }
  }
  if constexpr (EARLY) {
    const __bf16* Ap2 = Apan + (size_t)(tau + 2) * 64;
    const __bf16* Bp2 = Bpan + (size_t)(tau + 2) * 64;
    stage_q<false>(Ab, 0,   Ap2, K, w, l);   // A q0
    stage_q<false>(Ab, 128, Ap2, K, w, l);   // A q2
    stage_q<BMAP>(Bb, 0,   Bp2, K, w, l);    // B q0
    stage_q<BMAP>(Bb, 64,  Bp2, K, w, l);    // B q1
    stage_q<BMAP>(Bb, 128, Bp2, K, w, l);    // B q2
    stage_q<BMAP>(Bb, 192, Bp2, K, w, l);    // B q3
  }
  if constexpr (NEXT) LGKM(8); else LGKM(0);
  __builtin_amdgcn_s_setprio(1);
  #pragma unroll
  for (int mt = 0; mt < 4; ++mt)
    #pragma unroll
    for (int nt = 0; nt < 4; ++nt)
      acc[4 + mt][nt] = MFMA16(aB[mt], bB[nt], acc[4 + mt][nt]);
  __builtin_amdgcn_s_setprio(0);
  if constexpr (G3 >= 0) vmcnt_gate<G3>();
  BARRIER;
}

template <typename CT, int MODE>
__global__ __launch_bounds__(512, 2) void gemm256_kernel(const __bf16* __restrict__ A,
                                                         const __bf16* __restrict__ Bt,
                                                         CT* __restrict__ C, int M, int N, int K,
                                                         const float* __restrict__ cosT,
                                                         const float* __restrict__ sinT,
                                                         int Hh) {
  extern __shared__ __bf16 smem[];
  constexpr bool BMAP = (MODE == 1);

  // XCD-bijective block swizzle (all grids have nwg % 8 == 0)
  const int gx = gridDim.x;
  const int nwg = gx * gridDim.y;
  const int wg = blockIdx.y * gx + blockIdx.x;
  const int qq = nwg >> 3;
  const int id2 = (wg & 7) * qq + (wg >> 3);
  const int m0 = (id2 / gx) * 256, n0 = (id2 % gx) * 256;

  const int tid = threadIdx.x;
  const int l = tid & 63, w = tid >> 6;
  const int lo = l & 15, hi = l >> 4;
  const int wm = w >> 2, wn = w & 3;

  const __bf16* Apan = A + (size_t)m0 * K;
  const __bf16* Bpan = Bt + (size_t)n0 * K;

  f32x4 acc[8][4] = {};
  bf16x8 aA[4], aB[4], bA[4], bB[4];

  // prologue: stage tile0 (8 quanta) + tile1 (EARLY order first, LATE last);
  // vmcnt(8) = tile0 landed (per-wave) BEFORE barrier -> cross-wave visible after.
  stage_q<false>(smem,          0,   Apan, K, w, l);
  stage_q<false>(smem,          128, Apan, K, w, l);
  stage_q<BMAP>(smem + 16384,  0,   Bpan, K, w, l);
  stage_q<BMAP>(smem + 16384,  64,  Bpan, K, w, l);
  stage_q<BMAP>(smem + 16384,  128, Bpan, K, w, l);
  stage_q<BMAP>(smem + 16384,  192, Bpan, K, w, l);
  stage_q<false>(smem,          64,  Apan, K, w, l);
  stage_q<false>(smem,          192, Apan, K, w, l);
  stage_q<false>(smem + 32768,  0,   Apan + 64, K, w, l);
  stage_q<false>(smem + 32768,  128, Apan + 64, K, w, l);
  stage_q<BMAP>(smem + 49152,  0,   Bpan + 64, K, w, l);
  stage_q<BMAP>(smem + 49152,  64,  Bpan + 64, K, w, l);
  stage_q<BMAP>(smem + 49152,  128, Bpan + 64, K, w, l);
  stage_q<BMAP>(smem + 49152,  192, Bpan + 64, K, w, l);
  stage_q<false>(smem + 32768,  64,  Apan + 64, K, w, l);
  stage_q<false>(smem + 32768,  192, Apan + 64, K, w, l);
  vmcnt_gate<8>();
  BARRIER;

  #pragma unroll
  for (int t = 0; t < 4; ++t) {
    int ra = wm * 128 + t * 16 + lo;
    aA[t] = *(const bf16x8*)(smem + (size_t)ra * 64 + ((hi ^ (ra & 7)) << 3));
  }
  #pragma unroll
  for (int t = 0; t < 4; ++t) {
    int rb = wn * 64 + t * 16 + lo;
    bA[t] = *(const bf16x8*)(smem + 16384 + (size_t)rb * 64 + ((hi ^ (rb & 7)) << 3));
  }

  const int T = K >> 6;
  tile_body<false, true,  true,  2,  6, BMAP>(smem, Apan, Bpan, K, 0,     wm, wn, lo, hi, w, l, aA, aB, bA, bB, acc);
  for (int tau = 1; tau < T - 2; ++tau)
    tile_body<true, true,  true,  2,  6, BMAP>(smem, Apan, Bpan, K, tau,   wm, wn, lo, hi, w, l, aA, aB, bA, bB, acc);
  tile_body<true,  false, true,  2,  0, BMAP>(smem, Apan, Bpan, K, T - 2, wm, wn, lo, hi, w, l, aA, aB, bA, bB, acc);
  tile_body<false, false, false, -1, -1, BMAP>(smem, Apan, Bpan, K, T - 1, wm, wn, lo, hi, w, l, aA, aB, bA, bB, acc);

  if constexpr (MODE == 0) {
    // plain row-major C
    #pragma unroll
    for (int mt = 0; mt < 8; ++mt)
      #pragma unroll
      for (int nt = 0; nt < 4; ++nt) {
        int col = n0 + wn * 64 + nt * 16 + lo;
        #pragma unroll
        for (int r = 0; r < 4; ++r) {
          int row = m0 + wm * 128 + mt * 16 + 4 * hi + r;
          C[(size_t)row * N + col] = (CT)acc[mt][nt][r];
        }
      }
  } else if constexpr (MODE == 2) {
    // V: store to (b, kv, s, d); n-block == one KV head
    const int kv = n0 >> 8;
    #pragma unroll
    for (int mt = 0; mt < 8; ++mt)
      #pragma unroll
      for (int nt = 0; nt < 4; ++nt) {
        int col = wn * 64 + nt * 16 + lo;
        #pragma unroll
        for (int r = 0; r < 4; ++r) {
          int row = m0 + wm * 128 + mt * 16 + 4 * hi + r;
          int bb = row >> 12, sdx = row & 4095;
          C[(((size_t)(bb * Hh + kv)) * 4096 + sdx) * 256 + col] = (CT)acc[mt][nt][r];
        }
      }
  } else {
    // MODE 1: fused RoPE + store to (b, h, s, d). acc cols are colmap-permuted:
    // pair (nt, nt+1) = (d, d+128) with d = (2*wn + (nt>>1))*16 + lo.
    const int hq = n0 >> 8;
    #pragma unroll
    for (int mt = 0; mt < 8; ++mt)
      #pragma unroll
      for (int ntp = 0; ntp < 4; ntp += 2) {
        int d = (2 * wn + (ntp >> 1)) * 16 + lo;
        #pragma unroll
        for (int r = 0; r < 4; ++r) {
          int row = m0 + wm * 128 + mt * 16 + 4 * hi + r;
          int bb = row >> 12, sdx = row & 4095;
          float cc = cosT[(size_t)sdx * 128 + d];
          float ss = sinT[(size_t)sdx * 128 + d];
          float x1 = acc[mt][ntp][r], x2 = acc[mt][ntp + 1][r];
          size_t base = (((size_t)(bb * Hh + hq)) * 4096 + sdx) * 256;
          C[base + d]       = (CT)(x1 * cc - x2 * ss);
          C[base + d + 128] = (CT)(x1 * ss + x2 * cc);
        }
      }
  }
}

// ---------------- feature map (128-row blocks, grid x=32; best measured) ----------------
__global__ __launch_bounds__(256) void fm_kernel(const __bf16* __restrict__ rope,
                                                 const float* __restrict__ fm,
                                                 __bf16* __restrict__ out, int srcH, float scale) {
  __shared__ __bf16 fmT[64][256];  // [f][d] swizzled: group' = (d>>3) ^ (f&7)
  int bh = blockIdx.y;
  int h = bh & 15, b = bh >> 4;
  int s0 = blockIdx.x * 128;
  int tid = threadIdx.x, lane = tid & 63, wid = tid >> 6, hi = lane >> 4, lo = lane & 15;

  const float* fmh = fm + (size_t)h * 256 * 64;
  for (int i = tid; i < 256 * 64; i += 256) {
    int d = i >> 6, f = i & 63;
    fmT[f][(((d >> 3) ^ (f & 7)) << 3) | (d & 7)] = (__bf16)fmh[i];
  }
  __syncthreads();

  int srch = (srcH == 16) ? h : (h >> 1);
  const __bf16* abase = rope + ((size_t)(b * srcH + srch) * 4096 + s0 + 32 * wid) * 256;
  f32x4 acc[2][4] = {};
  for (int kk = 0; kk < 256; kk += 32) {
    bf16x8 a[2], bf[4];
    #pragma unroll
    for (int mt = 0; mt < 2; ++mt)
      a[mt] = *(const bf16x8*)(abase + (size_t)(16 * mt + lo) * 256 + kk + 8 * hi);
    const int G = (kk >> 3) + hi;
    #pragma unroll
    for (int nt = 0; nt < 4; ++nt) {
      int f = 16 * nt + lo;
      bf[nt] = *(const bf16x8*)&fmT[f][(G ^ (f & 7)) << 3];
    }
    #pragma unroll
    for (int mt = 0; mt < 2; ++mt)
      #pragma unroll
      for (int nt = 0; nt < 4; ++nt)
        acc[mt][nt] = MFMA16(a[mt], bf[nt], acc[mt][nt]);
  }

  size_t obase = ((size_t)(b * 16 + h) * 4096 + s0 + 32 * wid);
  #pragma unroll
  for (int mt = 0; mt < 2; ++mt) {
    #pragma unroll
    for (int r = 0; r < 4; ++r) {
      float z0 = acc[mt][0][r], z1 = acc[mt][1][r], z2 = acc[mt][2][r], z3 = acc[mt][3][r];
      float mx = fmaxf(fmaxf(z0, z1), fmaxf(z2, z3));
      float mn = fminf(fminf(z0, z1), fminf(z2, z3));
      #pragma unroll
      for (int off = 1; off < 16; off <<= 1) {
        mx = fmaxf(mx, __shfl_xor(mx, off));
        mn = fminf(mn, __shfl_xor(mn, off));
      }
      float ep0 = __expf(z0 - mx), ep1 = __expf(z1 - mx), ep2 = __expf(z2 - mx), ep3 = __expf(z3 - mx);
      float en0 = __expf(mn - z0), en1 = __expf(mn - z1), en2 = __expf(mn - z2), en3 = __expf(mn - z3);
      float sp = ep0 + ep1 + ep2 + ep3, sn = en0 + en1 + en2 + en3;
      #pragma unroll
      for (int off = 1; off < 16; off <<= 1) {
        sp += __shfl_xor(sp, off);
        sn += __shfl_xor(sn, off);
      }
      float rp = scale / sp, rn = scale / sn;
      int row = 16 * mt + 4 * hi + r;
      __bf16* op = out + (obase + row) * 128;
      op[0  + lo] = (__bf16)(ep0 * rp);  op[16 + lo] = (__bf16)(ep1 * rp);
      op[32 + lo] = (__bf16)(ep2 * rp);  op[48 + lo] = (__bf16)(ep3 * rp);
      op[64 + lo] = (__bf16)(en0 * rn);  op[80 + lo] = (__bf16)(en1 * rn);
      op[96 + lo] = (__bf16)(en2 * rn);  op[112 + lo] = (__bf16)(en3 * rn);
    }
  }
}

// ---------------- chunked linear attention (software-pipelined; best measured) ----------
// XCD swizzle (R7): dv-siblings share an XCD -> q/k head-slices L2-local.
// Pipeline (R8): double-buffered K/V, prefetch n+1 at top of n, light syncs.
__global__ __launch_bounds__(256) void attn_kernel(const __bf16* __restrict__ qf,
                                                   const __bf16* __restrict__ kf,
                                                   const __bf16* __restrict__ vp,
                                                   __bf16* __restrict__ o) {
  __shared__ __bf16 k_s[2][64][128];
  __shared__ __bf16 vT_s[2][32][64];
  __shared__ __bf16 sc_s[64][64];
  __shared__ __bf16 STb[32][128];

  int bid = blockIdx.x;
  int g   = ((bid >> 6) << 3) | (bid & 7);   // 0..31 = b*16 + h
  int dvb = (bid >> 3) & 7;
  int h = g & 15, b = g >> 4;
  int dv0 = dvb * 32;
  int tid = threadIdx.x, lane = tid & 63, wid = tid >> 6, hi = lane >> 4, lo = lane & 15;

  const __bf16* qh = qf + ((size_t)(b * 16 + h)) * 4096 * 128;
  const __bf16* kh = kf + ((size_t)(b * 16 + h)) * 4096 * 128;
  const __bf16* vh = vp + ((size_t)(b * 8 + (h >> 1))) * 4096 * 256 + dv0;
  __bf16* oh = o + ((size_t)b * 4096) * 4096 + h * 256 + dv0;

  {
    unsigned int* z = (unsigned int*)&STb[0][0];
    for (int i = tid; i < 2048; i += 256) z[i] = 0u;
  }
  f32x4 st[2][2] = {};

  const int vc = tid >> 2, vd8 = (tid & 3) * 8;
  bf16x8 aqN[4], aqC[4], vvN;

  // ---- prologue: K(0)->buf0, V(0)->reg, q(0)->reg; vT_s[0] write waits vv(0)
  // (FIFO => K(0) drained per-wave); lgkm(0)+barrier -> cross-wave visible.
  #pragma unroll
  for (int i = 0; i < 4; ++i) {
    int rb = (wid * 4 + i) * 4;
    int r = rb + (lane >> 4);
    int Glog = (lane & 15) ^ (r & 7);
    async_copy16(&k_s[0][rb][0], kh + (size_t)r * 128 + Glog * 8);
  }
  __builtin_amdgcn_sched_barrier(0);
  vvN = *(const bf16x8*)(vh + (size_t)vc * 256 + vd8);
  __builtin_amdgcn_sched_barrier(0);
  #pragma unroll
  for (int kq = 0; kq < 4; ++kq)
    aqN[kq] = *(const bf16x8*)(qh + (size_t)(16 * wid + lo) * 128 + 32 * kq + 8 * hi);
  __builtin_amdgcn_sched_barrier(0);
  #pragma unroll
  for (int j = 0; j < 8; ++j) {
    int dv = vd8 + j;
    vT_s[0][dv][(((vc >> 3) ^ (dv & 7)) << 3) | (vc & 7)] = vvN[j];
  }
  LGKM(0);
  BARRIER;

  for (int n = 0; n < 64; ++n) {
    const int buf = n & 1;
    const int s0 = n * 64;

    // consume q(n) (compiler waits the n-issued loads here), then prefetch n+1
    #pragma unroll
    for (int kq = 0; kq < 4; ++kq) aqC[kq] = aqN[kq];

    if (n < 63) {
      const int s1 = s0 + 64;
      #pragma unroll
      for (int i = 0; i < 4; ++i) {
        int rb = (wid * 4 + i) * 4;
        int r = rb + (lane >> 4);
        int Glog = (lane & 15) ^ (r & 7);
        async_copy16(&k_s[buf ^ 1][rb][0], kh + (size_t)(s1 + r) * 128 + Glog * 8);
      }
      __builtin_amdgcn_sched_barrier(0);
      vvN = *(const bf16x8*)(vh + (size_t)(s1 + vc) * 256 + vd8);
      __builtin_amdgcn_sched_barrier(0);
      #pragma unroll
      for (int kq = 0; kq < 4; ++kq)
        aqN[kq] = *(const bf16x8*)(qh + (size_t)(s1 + 16 * wid + lo) * 128 + 32 * kq + 8 * hi);
      __builtin_amdgcn_sched_barrier(0);
    }

    // ---- compute on buf: inter (q @ STb) + scores (q @ k)
    f32x4 acc_o[2] = {}, sacc[4] = {};
    #pragma unroll
    for (int nt = 0; nt < 2; ++nt)
      #pragma unroll
      for (int kq = 0; kq < 4; ++kq) {
        int rr = 16 * nt + lo, G = 4 * kq + hi;
        bf16x8 bf = *(const bf16x8*)&STb[rr][(G ^ (rr & 7)) << 3];
        acc_o[nt] = MFMA16(aqC[kq], bf, acc_o[nt]);
      }
    #pragma unroll
    for (int nt = 0; nt < 4; ++nt)
      #pragma unroll
      for (int kq = 0; kq < 4; ++kq) {
        int rr = 16 * nt + lo, G = 4 * kq + hi;
        bf16x8 bf = *(const bf16x8*)&k_s[buf][rr][(G ^ (rr & 7)) << 3];
        sacc[nt] = MFMA16(aqC[kq], bf, sacc[nt]);
      }
    // causal mask -> sc_s (wave-private 16-row band; intra-wave fence suffices)
    #pragma unroll
    for (int nt = 0; nt < 4; ++nt)
      #pragma unroll
      for (int r = 0; r < 4; ++r) {
        int c = 16 * wid + 4 * hi + r;
        int cp = 16 * nt + lo;
        float v = (cp <= c) ? sacc[nt][r] : 0.0f;
        sc_s[c][(((cp >> 3) ^ (c & 7)) << 3) | (cp & 7)] = (__bf16)v;
      }
    asm volatile("" ::: "memory");
    // intra: sc @ vT
    #pragma unroll
    for (int nt = 0; nt < 2; ++nt)
      #pragma unroll
      for (int kq = 0; kq < 2; ++kq) {
        int rA = 16 * wid + lo, GA = 4 * kq + hi;
        bf16x8 af = *(const bf16x8*)&sc_s[rA][(GA ^ (rA & 7)) << 3];
        int rB = 16 * nt + lo;
        bf16x8 bf = *(const bf16x8*)&vT_s[buf][rB][(GA ^ (rB & 7)) << 3];
        acc_o[nt] = MFMA16(af, bf, acc_o[nt]);
      }
    #pragma unroll
    for (int nt = 0; nt < 2; ++nt)
      #pragma unroll
      for (int r = 0; r < 4; ++r) {
        int c = 16 * wid + 4 * hi + r;
        oh[(size_t)(s0 + c) * 4096 + 16 * nt + lo] = (__bf16)acc_o[nt][r];
      }

    if (n == 63) break;   // ST update is dead on the last chunk

    BARRIER;  // mid: raw barrier (all pre-barrier LDS reads register-consumed)

    // ---- ST update: st += v^T @ k  (bu rebuilt from k_s[buf])
    bf16x8 bu[2][2];
    #pragma unroll
    for (int q = 0; q < 2; ++q) {
      int dk = 16 * (2 * wid + q) + lo;
      #pragma unroll
      for (int kq = 0; kq < 2; ++kq) {
        bf16x8 tmp;
        #pragma unroll
        for (int j = 0; j < 8; ++j) {
          int c = 32 * kq + 8 * hi + j;
          tmp[j] = k_s[buf][c][(((dk >> 3) ^ (c & 7)) << 3) | (dk & 7)];
        }
        bu[q][kq] = tmp;
      }
    }
    #pragma unroll
    for (int mt = 0; mt < 2; ++mt)
      #pragma unroll
      for (int kq = 0; kq < 2; ++kq) {
        int rA = 16 * mt + lo, GA = 4 * kq + hi;
        bf16x8 av = *(const bf16x8*)&vT_s[buf][rA][(GA ^ (rA & 7)) << 3];
        #pragma unroll
        for (int q = 0; q < 2; ++q)
          st[mt][q] = MFMA16(av, bu[q][kq], st[mt][q]);
      }
    #pragma unroll
    for (int mt = 0; mt < 2; ++mt)
      #pragma unroll
      for (int q = 0; q < 2; ++q) {
        int dk = 16 * (2 * wid + q) + lo;
        #pragma unroll
        for (int r = 0; r < 4; ++r) {
          int dvr = 16 * mt + 4 * hi + r;
          STb[dvr][(((dk >> 3) ^ (dvr & 7)) << 3) | (dk & 7)] = (__bf16)st[mt][q][r];
        }
      }
    // vT_s[buf^1] <- vv(n+1): compiler waits vv(n+1) => K(n+1) (older) drained
    #pragma unroll
    for (int j = 0; j < 8; ++j) {
      int dv = vd8 + j;
      vT_s[buf ^ 1][dv][(((vc >> 3) ^ (dv & 7)) << 3) | (vc & 7)] = vvN[j];
    }
    LGKM(0);   // ds_writes (STb, vT_s) visible cross-wave after barrier
    BARRIER;
  }
}

// ---------------- launch ----------------
extern "C" void kernel_launch(void* const* d_in, const int* in_sizes, int n_in,
                              void* d_out, int out_size, void* d_ws, size_t ws_size,
                              hipStream_t stream) {
  (void)in_sizes; (void)n_in; (void)out_size; (void)ws_size;
  const float* hs   = (const float*)d_in[0];
  const float* cosT = (const float*)d_in[1];
  const float* sinT = (const float*)d_in[2];
  const float* Wq   = (const float*)d_in[3];
  const float* Wk   = (const float*)d_in[4];
  const float* Wv   = (const float*)d_in[5];
  const float* Wo   = (const float*)d_in[6];
  const float* fmq  = (const float*)d_in[7];
  const float* fmk  = (const float*)d_in[8];
  float* out = (float*)d_out;
  char* ws = (char*)d_ws;

  hipFuncSetAttribute((const void*)gemm256_kernel<float, 0>,
                      hipFuncAttributeMaxDynamicSharedMemorySize, 131072);
  hipFuncSetAttribute((const void*)gemm256_kernel<__bf16, 1>,
                      hipFuncAttributeMaxDynamicSharedMemorySize, 131072);
  hipFuncSetAttribute((const void*)gemm256_kernel<__bf16, 2>,
                      hipFuncAttributeMaxDynamicSharedMemorySize, 131072);

  const size_t MB = 1024ull * 1024ull;
  __bf16* Xb   = (__bf16*)(ws + 0);
  __bf16* qfb  = (__bf16*)(ws + 0);
  __bf16* kfb  = (__bf16*)(ws + 34 * MB);
  __bf16* Wqt  = (__bf16*)(ws + 70 * MB);
  __bf16* ob   = (__bf16*)(ws + 70 * MB);
  __bf16* Wkt  = (__bf16*)(ws + 104 * MB);
  __bf16* Wvt  = (__bf16*)(ws + 119 * MB);
  __bf16* Wot  = (__bf16*)(ws + 140 * MB);
  __bf16* ropq = (__bf16*)(ws + 170 * MB);
  __bf16* ropk = (__bf16*)(ws + 238 * MB);
  __bf16* vpb  = (__bf16*)(ws + 272 * MB);

  convert_kernel<<<28672, 256, 0, stream>>>(hs, Xb, (size_t)8192 * 3584 / 4);
  transpose_kernel<<<dim3(128, 112), 256, 0, stream>>>(Wq, Wqt, 3584, 4096);
  transpose_kernel<<<dim3(64, 112),  256, 0, stream>>>(Wk, Wkt, 3584, 2048);
  transpose_kernel<<<dim3(64, 112),  256, 0, stream>>>(Wv, Wvt, 3584, 2048);
  transpose_kernel<<<dim3(112, 128), 256, 0, stream>>>(Wo, Wot, 4096, 3584);

  gemm256_kernel<__bf16, 1><<<dim3(16, 32), 512, 131072, stream>>>(
      Xb, Wqt, ropq, 8192, 4096, 3584, cosT, sinT, 16);
  gemm256_kernel<__bf16, 1><<<dim3(8, 32),  512, 131072, stream>>>(
      Xb, Wkt, ropk, 8192, 2048, 3584, cosT, sinT, 8);
  gemm256_kernel<__bf16, 2><<<dim3(8, 32),  512, 131072, stream>>>(
      Xb, Wvt, vpb, 8192, 2048, 3584, nullptr, nullptr, 8);

  fm_kernel<<<dim3(32, 32), 256, 0, stream>>>(ropq, fmq, qfb, 16, 0.08838834764831845f);
  fm_kernel<<<dim3(32, 32), 256, 0, stream>>>(ropk, fmk, kfb, 8, 1.0f);

  attn_kernel<<<256, 256, 0, stream>>>(qfb, kfb, vpb, ob);

  gemm256_kernel<float, 0><<<dim3(14, 32), 512, 131072, stream>>>(
      ob, Wot, out, 8192, 3584, 4096, nullptr, nullptr, 0);
}

// Round 14
// 920.288 us; speedup vs baseline: 1.0362x; 1.0107x over previous
//
#include <hip/hip_runtime.h>

// ---------------- types / helpers ----------------
typedef float  f32x4  __attribute__((ext_vector_type(4)));
typedef __bf16 bf16x4 __attribute__((ext_vector_type(4)));
typedef __bf16 bf16x8 __attribute__((ext_vector_type(8)));

#define MFMA16(a,b,c) __builtin_amdgcn_mfma_f32_16x16x32_bf16((a),(b),(c),0,0,0)

__device__ __forceinline__ void async_copy16(void* lds, const void* gmem) {
  __builtin_amdgcn_global_load_lds(
      (const __attribute__((address_space(1))) void*)gmem,
      (__attribute__((address_space(3))) void*)lds, 16, 0, 0);
}

template<int N> __device__ __forceinline__ void vmcnt_gate() {
  if constexpr (N == 8) asm volatile("s_waitcnt vmcnt(8)" ::: "memory");
  else if constexpr (N == 6) asm volatile("s_waitcnt vmcnt(6)" ::: "memory");
  else if constexpr (N == 4) asm volatile("s_waitcnt vmcnt(4)" ::: "memory");
  else if constexpr (N == 2) asm volatile("s_waitcnt vmcnt(2)" ::: "memory");
  else if constexpr (N == 0) asm volatile("s_waitcnt vmcnt(0)" ::: "memory");
  __builtin_amdgcn_sched_barrier(0);
}

// counted lgkm wait: drains all ds_reads OLDER than the N just issued (rule #18 fences)
#define LGKM(N) do { __builtin_amdgcn_sched_barrier(0); \
                     asm volatile("s_waitcnt lgkmcnt(" #N ")" ::: "memory"); \
                     __builtin_amdgcn_sched_barrier(0); } while (0)

#define BARRIER do { __builtin_amdgcn_sched_barrier(0); \
                     __builtin_amdgcn_s_barrier(); \
                     __builtin_amdgcn_sched_barrier(0); } while (0)

// ---------------- convert f32 -> bf16 ----------------
__global__ __launch_bounds__(256) void convert_kernel(const float* __restrict__ in,
                                                      __bf16* __restrict__ out, size_t n4) {
  size_t i = (size_t)blockIdx.x * 256 + threadIdx.x;
  if (i >= n4) return;
  f32x4 v = *(const f32x4*)(in + i * 4);
  bf16x4 o;
  #pragma unroll
  for (int j = 0; j < 4; ++j) o[j] = (__bf16)v[j];
  *(bf16x4*)(out + i * 4) = o;
}

// ---------------- transpose + convert: in f32 (R,C) -> out bf16 (C,R) ----------------
__global__ __launch_bounds__(256) void transpose_kernel(const float* __restrict__ in,
                                                        __bf16* __restrict__ out, int R, int C) {
  __shared__ float tile[32][33];
  int bx = blockIdx.x, by = blockIdx.y;
  int tx = threadIdx.x & 31, ty0 = threadIdx.x >> 5;
  #pragma unroll
  for (int i = 0; i < 4; ++i) {
    int r = by * 32 + ty0 + i * 8;
    tile[ty0 + i * 8][tx] = in[(size_t)r * C + bx * 32 + tx];
  }
  __syncthreads();
  #pragma unroll
  for (int i = 0; i < 4; ++i) {
    int c = bx * 32 + ty0 + i * 8;
    out[(size_t)c * R + by * 32 + tx] = (__bf16)tile[tx][ty0 + i * 8];
  }
}

// ---------------- 256x256 pipelined bf16 GEMM (FROZEN R5 schedule, 45% MfmaUtil) ------
// R14: body extracted into gemm_body<CT,MODE> (mechanical refactor, schedule untouched)
// so sibling dispatches can be merged into one launch (kill launch-boundary bubbles:
// 128KB LDS => 1 block/CU => each kernel is one block-wave; each boundary idles CUs
// for tail + ~3-6us turnaround). MODE epilogues: 0=plain, 1=RoPE fused, 2=V permuted.

template<bool REMAP>
__device__ __forceinline__ void stage_q(__bf16* region, int qrow, const __bf16* src,
                                        int K, int w, int l) {
  int s = qrow + w * 8 + (l >> 3);
  int gr = REMAP ? (((s >> 5) << 4) | (s & 15) | (((s >> 4) & 1) << 7)) : s;
  async_copy16(region + (size_t)(qrow + w * 8) * 64,
               src + (size_t)gr * K + (((l & 7) ^ (s & 7)) << 3));
}

template<bool LATE, bool EARLY, bool NEXT, int G2, int G3, bool BMAP>
__device__ __forceinline__ void tile_body(__bf16* smem,
                                          const __bf16* Apan, const __bf16* Bpan,
                                          int K, int tau, int wm, int wn,
                                          int lo, int hi, int w, int l,
                                          bf16x8 (&aA)[4], bf16x8 (&aB)[4],
                                          bf16x8 (&bA)[4], bf16x8 (&bB)[4],
                                          f32x4 (&acc)[8][4]) {
  const int buf = tau & 1;
  __bf16* Ab = smem + buf * 32768;
  __bf16* Bb = Ab + 16384;
  __bf16* An = smem + (buf ^ 1) * 32768;
  __bf16* Bn = An + 16384;

  // ---- block0: R1 = aB <- a(h1,k0)[buf]; S0 = LATE; lgkm(4) drains R0; M0 = aA*bA
  #pragma unroll
  for (int t = 0; t < 4; ++t) {
    int ra = wm * 128 + 64 + t * 16 + lo;
    aB[t] = *(const bf16x8*)(Ab + (size_t)ra * 64 + ((hi ^ (ra & 7)) << 3));
  }
  if constexpr (LATE) {
    const __bf16* Ap1 = Apan + (size_t)(tau + 1) * 64;
    stage_q<false>(An, 64,  Ap1, K, w, l);   // A q1
    stage_q<false>(An, 192, Ap1, K, w, l);   // A q3
  }
  LGKM(4);
  __builtin_amdgcn_s_setprio(1);
  #pragma unroll
  for (int mt = 0; mt < 4; ++mt)
    #pragma unroll
    for (int nt = 0; nt < 4; ++nt)
      acc[mt][nt] = MFMA16(aA[mt], bA[nt], acc[mt][nt]);
  __builtin_amdgcn_s_setprio(0);
  BARRIER;

  // ---- block1: R2 = aA <- a(h0,k1), bB <- b(k1) [buf]; lgkm(8) drains R1; M1 = aB*bA
  #pragma unroll
  for (int t = 0; t < 4; ++t) {
    int ra = wm * 128 + t * 16 + lo;
    aA[t] = *(const bf16x8*)(Ab + (size_t)ra * 64 + (((4 + hi) ^ (ra & 7)) << 3));
  }
  #pragma unroll
  for (int t = 0; t < 4; ++t) {
    int rb = wn * 64 + t * 16 + lo;
    bB[t] = *(const bf16x8*)(Bb + (size_t)rb * 64 + (((4 + hi) ^ (rb & 7)) << 3));
  }
  LGKM(8);
  __builtin_amdgcn_s_setprio(1);
  #pragma unroll
  for (int mt = 0; mt < 4; ++mt)
    #pragma unroll
    for (int nt = 0; nt < 4; ++nt)
      acc[4 + mt][nt] = MFMA16(aB[mt], bA[nt], acc[4 + mt][nt]);
  __builtin_amdgcn_s_setprio(0);
  BARRIER;

  // ---- block2: R3 = aB <- a(h1,k1)[buf]; lgkm(4) drains R2; M2 = aA*bB;
  //      G2 gate BEFORE bar2 (cross-wave: EARLY(tau+1) landed for everyone)
  #pragma unroll
  for (int t = 0; t < 4; ++t) {
    int ra = wm * 128 + 64 + t * 16 + lo;
    aB[t] = *(const bf16x8*)(Ab + (size_t)ra * 64 + (((4 + hi) ^ (ra & 7)) << 3));
  }
  LGKM(4);
  __builtin_amdgcn_s_setprio(1);
  #pragma unroll
  for (int mt = 0; mt < 4; ++mt)
    #pragma unroll
    for (int nt = 0; nt < 4; ++nt)
      acc[mt][nt] = MFMA16(aA[mt], bB[nt], acc[mt][nt]);
  __builtin_amdgcn_s_setprio(0);
  if constexpr (G2 >= 0) vmcnt_gate<G2>();
  BARRIER;

  // ---- block3: R0' = aA <- a(h0,k0), bA <- b(k0) [nbuf] (NEXT); S3 = EARLY(tau+2 -> buf);
  //      lgkm(8|0) drains R3; M3 = aB*bB; G3 gate BEFORE bar3 (LATE landed for everyone)
  if constexpr (NEXT) {
    #pragma unroll
    for (int t = 0; t < 4; ++t) {
      int ra = wm * 128 + t * 16 + lo;
      aA[t] = *(const bf16x8*)(An + (size_t)ra * 64 + ((hi ^ (ra & 7)) << 3));
    }
    #pragma unroll
    for (int t = 0; t < 4; ++t) {
      int rb = wn * 64 + t * 16 + lo;
      bA[t] = *(const bf16x8*)(Bn + (size_t)rb * 64 + ((hi ^ (rb & 7)) << 3));
    }
  }
  if constexpr (EARLY) {
    const __bf16* Ap2 = Apan + (size_t)(tau + 2) * 64;
    const __bf16* Bp2 = Bpan + (size_t)(tau + 2) * 64;
    stage_q<false>(Ab, 0,   Ap2, K, w, l);   // A q0
    stage_q<false>(Ab, 128, Ap2, K, w, l);   // A q2
    stage_q<BMAP>(Bb, 0,   Bp2, K, w, l);    // B q0
    stage_q<BMAP>(Bb, 64,  Bp2, K, w, l);    // B q1
    stage_q<BMAP>(Bb, 128, Bp2, K, w, l);    // B q2
    stage_q<BMAP>(Bb, 192, Bp2, K, w, l);    // B q3
  }
  if constexpr (NEXT) LGKM(8); else LGKM(0);
  __builtin_amdgcn_s_setprio(1);
  #pragma unroll
  for (int mt = 0; mt < 4; ++mt)
    #pragma unroll
    for (int nt = 0; nt < 4; ++nt)
      acc[4 + mt][nt] = MFMA16(aB[mt], bB[nt], acc[4 + mt][nt]);
  __builtin_amdgcn_s_setprio(0);
  if constexpr (G3 >= 0) vmcnt_gate<G3>();
  BARRIER;
}

template <typename CT, int MODE>
__device__ __forceinline__ void gemm_body(const __bf16* __restrict__ A,
                                          const __bf16* __restrict__ Bt,
                                          CT* __restrict__ C, int M, int N, int K,
                                          const float* __restrict__ cosT,
                                          const float* __restrict__ sinT,
                                          int Hh, __bf16* smem, int m0, int n0) {
  constexpr bool BMAP = (MODE == 1);

  const int tid = threadIdx.x;
  const int l = tid & 63, w = tid >> 6;
  const int lo = l & 15, hi = l >> 4;
  const int wm = w >> 2, wn = w & 3;

  const __bf16* Apan = A + (size_t)m0 * K;
  const __bf16* Bpan = Bt + (size_t)n0 * K;

  f32x4 acc[8][4] = {};
  bf16x8 aA[4], aB[4], bA[4], bB[4];

  // prologue: stage tile0 (8 quanta) + tile1 (EARLY order first, LATE last);
  // vmcnt(8) = tile0 landed (per-wave) BEFORE barrier -> cross-wave visible after.
  stage_q<false>(smem,          0,   Apan, K, w, l);
  stage_q<false>(smem,          128, Apan, K, w, l);
  stage_q<BMAP>(smem + 16384,  0,   Bpan, K, w, l);
  stage_q<BMAP>(smem + 16384,  64,  Bpan, K, w, l);
  stage_q<BMAP>(smem + 16384,  128, Bpan, K, w, l);
  stage_q<BMAP>(smem + 16384,  192, Bpan, K, w, l);
  stage_q<false>(smem,          64,  Apan, K, w, l);
  stage_q<false>(smem,          192, Apan, K, w, l);
  stage_q<false>(smem + 32768,  0,   Apan + 64, K, w, l);
  stage_q<false>(smem + 32768,  128, Apan + 64, K, w, l);
  stage_q<BMAP>(smem + 49152,  0,   Bpan + 64, K, w, l);
  stage_q<BMAP>(smem + 49152,  64,  Bpan + 64, K, w, l);
  stage_q<BMAP>(smem + 49152,  128, Bpan + 64, K, w, l);
  stage_q<BMAP>(smem + 49152,  192, Bpan + 64, K, w, l);
  stage_q<false>(smem + 32768,  64,  Apan + 64, K, w, l);
  stage_q<false>(smem + 32768,  192, Apan + 64, K, w, l);
  vmcnt_gate<8>();
  BARRIER;

  #pragma unroll
  for (int t = 0; t < 4; ++t) {
    int ra = wm * 128 + t * 16 + lo;
    aA[t] = *(const bf16x8*)(smem + (size_t)ra * 64 + ((hi ^ (ra & 7)) << 3));
  }
  #pragma unroll
  for (int t = 0; t < 4; ++t) {
    int rb = wn * 64 + t * 16 + lo;
    bA[t] = *(const bf16x8*)(smem + 16384 + (size_t)rb * 64 + ((hi ^ (rb & 7)) << 3));
  }

  const int T = K >> 6;
  tile_body<false, true,  true,  2,  6, BMAP>(smem, Apan, Bpan, K, 0,     wm, wn, lo, hi, w, l, aA, aB, bA, bB, acc);
  for (int tau = 1; tau < T - 2; ++tau)
    tile_body<true, true,  true,  2,  6, BMAP>(smem, Apan, Bpan, K, tau,   wm, wn, lo, hi, w, l, aA, aB, bA, bB, acc);
  tile_body<true,  false, true,  2,  0, BMAP>(smem, Apan, Bpan, K, T - 2, wm, wn, lo, hi, w, l, aA, aB, bA, bB, acc);
  tile_body<false, false, false, -1, -1, BMAP>(smem, Apan, Bpan, K, T - 1, wm, wn, lo, hi, w, l, aA, aB, bA, bB, acc);

  if constexpr (MODE == 0) {
    // plain row-major C
    #pragma unroll
    for (int mt = 0; mt < 8; ++mt)
      #pragma unroll
      for (int nt = 0; nt < 4; ++nt) {
        int col = n0 + wn * 64 + nt * 16 + lo;
        #pragma unroll
        for (int r = 0; r < 4; ++r) {
          int row = m0 + wm * 128 + mt * 16 + 4 * hi + r;
          C[(size_t)row * N + col] = (CT)acc[mt][nt][r];
        }
      }
  } else if constexpr (MODE == 2) {
    // V: store to (b, kv, s, d); n-block == one KV head
    const int kv = n0 >> 8;
    #pragma unroll
    for (int mt = 0; mt < 8; ++mt)
      #pragma unroll
      for (int nt = 0; nt < 4; ++nt) {
        int col = wn * 64 + nt * 16 + lo;
        #pragma unroll
        for (int r = 0; r < 4; ++r) {
          int row = m0 + wm * 128 + mt * 16 + 4 * hi + r;
          int bb = row >> 12, sdx = row & 4095;
          C[(((size_t)(bb * Hh + kv)) * 4096 + sdx) * 256 + col] = (CT)acc[mt][nt][r];
        }
      }
  } else {
    // MODE 1: fused RoPE + store to (b, h, s, d). acc cols are colmap-permuted:
    // pair (nt, nt+1) = (d, d+128) with d = (2*wn + (nt>>1))*16 + lo.
    const int hq = n0 >> 8;
    #pragma unroll
    for (int mt = 0; mt < 8; ++mt)
      #pragma unroll
      for (int ntp = 0; ntp < 4; ntp += 2) {
        int d = (2 * wn + (ntp >> 1)) * 16 + lo;
        #pragma unroll
        for (int r = 0; r < 4; ++r) {
          int row = m0 + wm * 128 + mt * 16 + 4 * hi + r;
          int bb = row >> 12, sdx = row & 4095;
          float cc = cosT[(size_t)sdx * 128 + d];
          float ss = sinT[(size_t)sdx * 128 + d];
          float x1 = acc[mt][ntp][r], x2 = acc[mt][ntp + 1][r];
          size_t base = (((size_t)(bb * Hh + hq)) * 4096 + sdx) * 256;
          C[base + d]       = (CT)(x1 * cc - x2 * ss);
          C[base + d + 128] = (CT)(x1 * ss + x2 * cc);
        }
      }
  }
}

template <typename CT, int MODE>
__global__ __launch_bounds__(512, 2) void gemm256_kernel(const __bf16* __restrict__ A,
                                                         const __bf16* __restrict__ Bt,
                                                         CT* __restrict__ C, int M, int N, int K,
                                                         const float* __restrict__ cosT,
                                                         const float* __restrict__ sinT,
                                                         int Hh) {
  extern __shared__ __bf16 smem[];
  // XCD-bijective block swizzle (all grids have nwg % 8 == 0)
  const int gx = gridDim.x;
  const int nwg = gx * gridDim.y;
  const int wg = blockIdx.y * gx + blockIdx.x;
  const int qq = nwg >> 3;
  const int id2 = (wg & 7) * qq + (wg >> 3);
  const int m0 = (id2 / gx) * 256, n0 = (id2 % gx) * 256;
  gemm_body<CT, MODE>(A, Bt, C, M, N, K, cosT, sinT, Hh, smem, m0, n0);
}

// merged K+V GEMM: grid (8, 64); y<32 = K (MODE1, RoPE), y>=32 = V (MODE2).
// Per-half swizzle identical to the original dim3(8,32) launches (nwg=256) ->
// same tile assignment, same XCD alignment ((256+wg)%8 == wg%8).
__global__ __launch_bounds__(512, 2) void gemm256kv_kernel(const __bf16* __restrict__ A,
                                                           const __bf16* __restrict__ Bk,
                                                           __bf16* __restrict__ Ck,
                                                           const __bf16* __restrict__ Bv,
                                                           __bf16* __restrict__ Cv,
                                                           int M, int N, int K,
                                                           const float* __restrict__ cosT,
                                                           const float* __restrict__ sinT) {
  extern __shared__ __bf16 smem[];
  const int half = blockIdx.y >> 5;
  const int by = blockIdx.y & 31;
  const int gx = gridDim.x;          // 8
  const int nwg = gx * 32;           // 256 per half
  const int wg = by * gx + blockIdx.x;
  const int qq = nwg >> 3;
  const int id2 = (wg & 7) * qq + (wg >> 3);
  const int m0 = (id2 / gx) * 256, n0 = (id2 % gx) * 256;
  if (half == 0)
    gemm_body<__bf16, 1>(A, Bk, Ck, M, N, K, cosT, sinT, 8, smem, m0, n0);
  else
    gemm_body<__bf16, 2>(A, Bv, Cv, M, N, K, nullptr, nullptr, 8, smem, m0, n0);
}

// ---------------- feature map (merged q+k: grid (32, 64); y>=32 = k path) -------------
__global__ __launch_bounds__(256) void fm_kernel(const __bf16* __restrict__ ropq,
                                                 const __bf16* __restrict__ ropk,
                                                 const float* __restrict__ fmq,
                                                 const float* __restrict__ fmk,
                                                 __bf16* __restrict__ outq,
                                                 __bf16* __restrict__ outk) {
  __shared__ __bf16 fmT[64][256];  // [f][d] swizzled: group' = (d>>3) ^ (f&7)
  const int half = blockIdx.y >> 5;
  const __bf16* rope = half ? ropk : ropq;
  const float* fm = half ? fmk : fmq;
  __bf16* out = half ? outk : outq;
  const int srcH = half ? 8 : 16;
  const float scale = half ? 1.0f : 0.08838834764831845f;

  int bh = blockIdx.y & 31;
  int h = bh & 15, b = bh >> 4;
  int s0 = blockIdx.x * 128;
  int tid = threadIdx.x, lane = tid & 63, wid = tid >> 6, hi = lane >> 4, lo = lane & 15;

  const float* fmh = fm + (size_t)h * 256 * 64;
  for (int i = tid; i < 256 * 64; i += 256) {
    int d = i >> 6, f = i & 63;
    fmT[f][(((d >> 3) ^ (f & 7)) << 3) | (d & 7)] = (__bf16)fmh[i];
  }
  __syncthreads();

  int srch = (srcH == 16) ? h : (h >> 1);
  const __bf16* abase = rope + ((size_t)(b * srcH + srch) * 4096 + s0 + 32 * wid) * 256;
  f32x4 acc[2][4] = {};
  for (int kk = 0; kk < 256; kk += 32) {
    bf16x8 a[2], bf[4];
    #pragma unroll
    for (int mt = 0; mt < 2; ++mt)
      a[mt] = *(const bf16x8*)(abase + (size_t)(16 * mt + lo) * 256 + kk + 8 * hi);
    const int G = (kk >> 3) + hi;
    #pragma unroll
    for (int nt = 0; nt < 4; ++nt) {
      int f = 16 * nt + lo;
      bf[nt] = *(const bf16x8*)&fmT[f][(G ^ (f & 7)) << 3];
    }
    #pragma unroll
    for (int mt = 0; mt < 2; ++mt)
      #pragma unroll
      for (int nt = 0; nt < 4; ++nt)
        acc[mt][nt] = MFMA16(a[mt], bf[nt], acc[mt][nt]);
  }

  size_t obase = ((size_t)(b * 16 + h) * 4096 + s0 + 32 * wid);
  #pragma unroll
  for (int mt = 0; mt < 2; ++mt) {
    #pragma unroll
    for (int r = 0; r < 4; ++r) {
      float z0 = acc[mt][0][r], z1 = acc[mt][1][r], z2 = acc[mt][2][r], z3 = acc[mt][3][r];
      float mx = fmaxf(fmaxf(z0, z1), fmaxf(z2, z3));
      float mn = fminf(fminf(z0, z1), fminf(z2, z3));
      #pragma unroll
      for (int off = 1; off < 16; off <<= 1) {
        mx = fmaxf(mx, __shfl_xor(mx, off));
        mn = fminf(mn, __shfl_xor(mn, off));
      }
      float ep0 = __expf(z0 - mx), ep1 = __expf(z1 - mx), ep2 = __expf(z2 - mx), ep3 = __expf(z3 - mx);
      float en0 = __expf(mn - z0), en1 = __expf(mn - z1), en2 = __expf(mn - z2), en3 = __expf(mn - z3);
      float sp = ep0 + ep1 + ep2 + ep3, sn = en0 + en1 + en2 + en3;
      #pragma unroll
      for (int off = 1; off < 16; off <<= 1) {
        sp += __shfl_xor(sp, off);
        sn += __shfl_xor(sn, off);
      }
      float rp = scale / sp, rn = scale / sn;
      int row = 16 * mt + 4 * hi + r;
      __bf16* op = out + (obase + row) * 128;
      op[0  + lo] = (__bf16)(ep0 * rp);  op[16 + lo] = (__bf16)(ep1 * rp);
      op[32 + lo] = (__bf16)(ep2 * rp);  op[48 + lo] = (__bf16)(ep3 * rp);
      op[64 + lo] = (__bf16)(en0 * rn);  op[80 + lo] = (__bf16)(en1 * rn);
      op[96 + lo] = (__bf16)(en2 * rn);  op[112 + lo] = (__bf16)(en3 * rn);
    }
  }
}

// ---------------- chunked linear attention (software-pipelined; best measured) ----------
// XCD swizzle (R7): dv-siblings share an XCD -> q/k head-slices L2-local.
// Pipeline (R8): double-buffered K/V, prefetch n+1 at top of n, light syncs.
__global__ __launch_bounds__(256) void attn_kernel(const __bf16* __restrict__ qf,
                                                   const __bf16* __restrict__ kf,
                                                   const __bf16* __restrict__ vp,
                                                   __bf16* __restrict__ o) {
  __shared__ __bf16 k_s[2][64][128];
  __shared__ __bf16 vT_s[2][32][64];
  __shared__ __bf16 sc_s[64][64];
  __shared__ __bf16 STb[32][128];

  int bid = blockIdx.x;
  int g   = ((bid >> 6) << 3) | (bid & 7);   // 0..31 = b*16 + h
  int dvb = (bid >> 3) & 7;
  int h = g & 15, b = g >> 4;
  int dv0 = dvb * 32;
  int tid = threadIdx.x, lane = tid & 63, wid = tid >> 6, hi = lane >> 4, lo = lane & 15;

  const __bf16* qh = qf + ((size_t)(b * 16 + h)) * 4096 * 128;
  const __bf16* kh = kf + ((size_t)(b * 16 + h)) * 4096 * 128;
  const __bf16* vh = vp + ((size_t)(b * 8 + (h >> 1))) * 4096 * 256 + dv0;
  __bf16* oh = o + ((size_t)b * 4096) * 4096 + h * 256 + dv0;

  {
    unsigned int* z = (unsigned int*)&STb[0][0];
    for (int i = tid; i < 2048; i += 256) z[i] = 0u;
  }
  f32x4 st[2][2] = {};

  const int vc = tid >> 2, vd8 = (tid & 3) * 8;
  bf16x8 aqN[4], aqC[4], vvN;

  // ---- prologue: K(0)->buf0, V(0)->reg, q(0)->reg; vT_s[0] write waits vv(0)
  // (FIFO => K(0) drained per-wave); lgkm(0)+barrier -> cross-wave visible.
  #pragma unroll
  for (int i = 0; i < 4; ++i) {
    int rb = (wid * 4 + i) * 4;
    int r = rb + (lane >> 4);
    int Glog = (lane & 15) ^ (r & 7);
    async_copy16(&k_s[0][rb][0], kh + (size_t)r * 128 + Glog * 8);
  }
  __builtin_amdgcn_sched_barrier(0);
  vvN = *(const bf16x8*)(vh + (size_t)vc * 256 + vd8);
  __builtin_amdgcn_sched_barrier(0);
  #pragma unroll
  for (int kq = 0; kq < 4; ++kq)
    aqN[kq] = *(const bf16x8*)(qh + (size_t)(16 * wid + lo) * 128 + 32 * kq + 8 * hi);
  __builtin_amdgcn_sched_barrier(0);
  #pragma unroll
  for (int j = 0; j < 8; ++j) {
    int dv = vd8 + j;
    vT_s[0][dv][(((vc >> 3) ^ (dv & 7)) << 3) | (vc & 7)] = vvN[j];
  }
  LGKM(0);
  BARRIER;

  for (int n = 0; n < 64; ++n) {
    const int buf = n & 1;
    const int s0 = n * 64;

    // consume q(n) (compiler waits the n-issued loads here), then prefetch n+1
    #pragma unroll
    for (int kq = 0; kq < 4; ++kq) aqC[kq] = aqN[kq];

    if (n < 63) {
      const int s1 = s0 + 64;
      #pragma unroll
      for (int i = 0; i < 4; ++i) {
        int rb = (wid * 4 + i) * 4;
        int r = rb + (lane >> 4);
        int Glog = (lane & 15) ^ (r & 7);
        async_copy16(&k_s[buf ^ 1][rb][0], kh + (size_t)(s1 + r) * 128 + Glog * 8);
      }
      __builtin_amdgcn_sched_barrier(0);
      vvN = *(const bf16x8*)(vh + (size_t)(s1 + vc) * 256 + vd8);
      __builtin_amdgcn_sched_barrier(0);
      #pragma unroll
      for (int kq = 0; kq < 4; ++kq)
        aqN[kq] = *(const bf16x8*)(qh + (size_t)(s1 + 16 * wid + lo) * 128 + 32 * kq + 8 * hi);
      __builtin_amdgcn_sched_barrier(0);
    }

    // ---- compute on buf: inter (q @ STb) + scores (q @ k)
    f32x4 acc_o[2] = {}, sacc[4] = {};
    #pragma unroll
    for (int nt = 0; nt < 2; ++nt)
      #pragma unroll
      for (int kq = 0; kq < 4; ++kq) {
        int rr = 16 * nt + lo, G = 4 * kq + hi;
        bf16x8 bf = *(const bf16x8*)&STb[rr][(G ^ (rr & 7)) << 3];
        acc_o[nt] = MFMA16(aqC[kq], bf, acc_o[nt]);
      }
    #pragma unroll
    for (int nt = 0; nt < 4; ++nt)
      #pragma unroll
      for (int kq = 0; kq < 4; ++kq) {
        int rr = 16 * nt + lo, G = 4 * kq + hi;
        bf16x8 bf = *(const bf16x8*)&k_s[buf][rr][(G ^ (rr & 7)) << 3];
        sacc[nt] = MFMA16(aqC[kq], bf, sacc[nt]);
      }
    // causal mask -> sc_s (wave-private 16-row band; intra-wave fence suffices)
    #pragma unroll
    for (int nt = 0; nt < 4; ++nt)
      #pragma unroll
      for (int r = 0; r < 4; ++r) {
        int c = 16 * wid + 4 * hi + r;
        int cp = 16 * nt + lo;
        float v = (cp <= c) ? sacc[nt][r] : 0.0f;
        sc_s[c][(((cp >> 3) ^ (c & 7)) << 3) | (cp & 7)] = (__bf16)v;
      }
    asm volatile("" ::: "memory");
    // intra: sc @ vT
    #pragma unroll
    for (int nt = 0; nt < 2; ++nt)
      #pragma unroll
      for (int kq = 0; kq < 2; ++kq) {
        int rA = 16 * wid + lo, GA = 4 * kq + hi;
        bf16x8 af = *(const bf16x8*)&sc_s[rA][(GA ^ (rA & 7)) << 3];
        int rB = 16 * nt + lo;
        bf16x8 bf = *(const bf16x8*)&vT_s[buf][rB][(GA ^ (rB & 7)) << 3];
        acc_o[nt] = MFMA16(af, bf, acc_o[nt]);
      }
    #pragma unroll
    for (int nt = 0; nt < 2; ++nt)
      #pragma unroll
      for (int r = 0; r < 4; ++r) {
        int c = 16 * wid + 4 * hi + r;
        oh[(size_t)(s0 + c) * 4096 + 16 * nt + lo] = (__bf16)acc_o[nt][r];
      }

    if (n == 63) break;   // ST update is dead on the last chunk

    BARRIER;  // mid: raw barrier (all pre-barrier LDS reads register-consumed)

    // ---- ST update: st += v^T @ k  (bu rebuilt from k_s[buf])
    bf16x8 bu[2][2];
    #pragma unroll
    for (int q = 0; q < 2; ++q) {
      int dk = 16 * (2 * wid + q) + lo;
      #pragma unroll
      for (int kq = 0; kq < 2; ++kq) {
        bf16x8 tmp;
        #pragma unroll
        for (int j = 0; j < 8; ++j) {
          int c = 32 * kq + 8 * hi + j;
          tmp[j] = k_s[buf][c][(((dk >> 3) ^ (c & 7)) << 3) | (dk & 7)];
        }
        bu[q][kq] = tmp;
      }
    }
    #pragma unroll
    for (int mt = 0; mt < 2; ++mt)
      #pragma unroll
      for (int kq = 0; kq < 2; ++kq) {
        int rA = 16 * mt + lo, GA = 4 * kq + hi;
        bf16x8 av = *(const bf16x8*)&vT_s[buf][rA][(GA ^ (rA & 7)) << 3];
        #pragma unroll
        for (int q = 0; q < 2; ++q)
          st[mt][q] = MFMA16(av, bu[q][kq], st[mt][q]);
      }
    #pragma unroll
    for (int mt = 0; mt < 2; ++mt)
      #pragma unroll
      for (int q = 0; q < 2; ++q) {
        int dk = 16 * (2 * wid + q) + lo;
        #pragma unroll
        for (int r = 0; r < 4; ++r) {
          int dvr = 16 * mt + 4 * hi + r;
          STb[dvr][(((dk >> 3) ^ (dvr & 7)) << 3) | (dk & 7)] = (__bf16)st[mt][q][r];
        }
      }
    // vT_s[buf^1] <- vv(n+1): compiler waits vv(n+1) => K(n+1) (older) drained
    #pragma unroll
    for (int j = 0; j < 8; ++j) {
      int dv = vd8 + j;
      vT_s[buf ^ 1][dv][(((vc >> 3) ^ (dv & 7)) << 3) | (vc & 7)] = vvN[j];
    }
    LGKM(0);   // ds_writes (STb, vT_s) visible cross-wave after barrier
    BARRIER;
  }
}

// ---------------- launch ----------------
extern "C" void kernel_launch(void* const* d_in, const int* in_sizes, int n_in,
                              void* d_out, int out_size, void* d_ws, size_t ws_size,
                              hipStream_t stream) {
  (void)in_sizes; (void)n_in; (void)out_size; (void)ws_size;
  const float* hs   = (const float*)d_in[0];
  const float* cosT = (const float*)d_in[1];
  const float* sinT = (const float*)d_in[2];
  const float* Wq   = (const float*)d_in[3];
  const float* Wk   = (const float*)d_in[4];
  const float* Wv   = (const float*)d_in[5];
  const float* Wo   = (const float*)d_in[6];
  const float* fmq  = (const float*)d_in[7];
  const float* fmk  = (const float*)d_in[8];
  float* out = (float*)d_out;
  char* ws = (char*)d_ws;

  hipFuncSetAttribute((const void*)gemm256_kernel<float, 0>,
                      hipFuncAttributeMaxDynamicSharedMemorySize, 131072);
  hipFuncSetAttribute((const void*)gemm256_kernel<__bf16, 1>,
                      hipFuncAttributeMaxDynamicSharedMemorySize, 131072);
  hipFuncSetAttribute((const void*)gemm256kv_kernel,
                      hipFuncAttributeMaxDynamicSharedMemorySize, 131072);

  const size_t MB = 1024ull * 1024ull;
  __bf16* Xb   = (__bf16*)(ws + 0);
  __bf16* qfb  = (__bf16*)(ws + 0);
  __bf16* kfb  = (__bf16*)(ws + 34 * MB);
  __bf16* Wqt  = (__bf16*)(ws + 70 * MB);
  __bf16* ob   = (__bf16*)(ws + 70 * MB);
  __bf16* Wkt  = (__bf16*)(ws + 104 * MB);
  __bf16* Wvt  = (__bf16*)(ws + 119 * MB);
  __bf16* Wot  = (__bf16*)(ws + 140 * MB);
  __bf16* ropq = (__bf16*)(ws + 170 * MB);
  __bf16* ropk = (__bf16*)(ws + 238 * MB);
  __bf16* vpb  = (__bf16*)(ws + 272 * MB);

  convert_kernel<<<28672, 256, 0, stream>>>(hs, Xb, (size_t)8192 * 3584 / 4);
  transpose_kernel<<<dim3(128, 112), 256, 0, stream>>>(Wq, Wqt, 3584, 4096);
  transpose_kernel<<<dim3(64, 112),  256, 0, stream>>>(Wk, Wkt, 3584, 2048);
  transpose_kernel<<<dim3(64, 112),  256, 0, stream>>>(Wv, Wvt, 3584, 2048);
  transpose_kernel<<<dim3(112, 128), 256, 0, stream>>>(Wo, Wot, 4096, 3584);

  gemm256_kernel<__bf16, 1><<<dim3(16, 32), 512, 131072, stream>>>(
      Xb, Wqt, ropq, 8192, 4096, 3584, cosT, sinT, 16);
  gemm256kv_kernel<<<dim3(8, 64), 512, 131072, stream>>>(
      Xb, Wkt, ropk, Wvt, vpb, 8192, 2048, 3584, cosT, sinT);

  fm_kernel<<<dim3(32, 64), 256, 0, stream>>>(ropq, ropk, fmq, fmk, qfb, kfb);

  attn_kernel<<<256, 256, 0, stream>>>(qfb, kfb, vpb, ob);

  gemm256_kernel<float, 0><<<dim3(14, 32), 512, 131072, stream>>>(
      ob, Wot, out, 8192, 3584, 4096, nullptr, nullptr, 0);
}

// Round 15
// 902.123 us; speedup vs baseline: 1.0571x; 1.0201x over previous
//
#include <hip/hip_runtime.h>

// ---------------- types / helpers ----------------
typedef float  f32x4  __attribute__((ext_vector_type(4)));
typedef __bf16 bf16x4 __attribute__((ext_vector_type(4)));
typedef __bf16 bf16x8 __attribute__((ext_vector_type(8)));

#define MFMA16(a,b,c) __builtin_amdgcn_mfma_f32_16x16x32_bf16((a),(b),(c),0,0,0)

__device__ __forceinline__ void async_copy16(void* lds, const void* gmem) {
  __builtin_amdgcn_global_load_lds(
      (const __attribute__((address_space(1))) void*)gmem,
      (__attribute__((address_space(3))) void*)lds, 16, 0, 0);
}

template<int N> __device__ __forceinline__ void vmcnt_gate() {
  if constexpr (N == 8) asm volatile("s_waitcnt vmcnt(8)" ::: "memory");
  else if constexpr (N == 6) asm volatile("s_waitcnt vmcnt(6)" ::: "memory");
  else if constexpr (N == 4) asm volatile("s_waitcnt vmcnt(4)" ::: "memory");
  else if constexpr (N == 2) asm volatile("s_waitcnt vmcnt(2)" ::: "memory");
  else if constexpr (N == 0) asm volatile("s_waitcnt vmcnt(0)" ::: "memory");
  __builtin_amdgcn_sched_barrier(0);
}

// counted lgkm wait: drains all ds_reads OLDER than the N just issued (rule #18 fences)
#define LGKM(N) do { __builtin_amdgcn_sched_barrier(0); \
                     asm volatile("s_waitcnt lgkmcnt(" #N ")" ::: "memory"); \
                     __builtin_amdgcn_sched_barrier(0); } while (0)

#define BARRIER do { __builtin_amdgcn_sched_barrier(0); \
                     __builtin_amdgcn_s_barrier(); \
                     __builtin_amdgcn_sched_barrier(0); } while (0)

// ---------------- merged prologue: convert + 4 weight transposes (R15) ----------------
// All 5 sub-kernels are independent (disjoint reads/writes); merging kills 4 launch
// boundaries (each = tail drain + ~3-5us CP turnaround at 1 block/CU). 1-D grid range
// decode reproduces each original (bx,by) exactly; branches are block-uniform.

__device__ __forceinline__ void transpose_body(const float* __restrict__ in,
                                               __bf16* __restrict__ out, int R, int C,
                                               int bx, int by, float (&tile)[32][33]) {
  int tx = threadIdx.x & 31, ty0 = threadIdx.x >> 5;
  #pragma unroll
  for (int i = 0; i < 4; ++i) {
    int r = by * 32 + ty0 + i * 8;
    tile[ty0 + i * 8][tx] = in[(size_t)r * C + bx * 32 + tx];
  }
  __syncthreads();
  #pragma unroll
  for (int i = 0; i < 4; ++i) {
    int c = bx * 32 + ty0 + i * 8;
    out[(size_t)c * R + by * 32 + tx] = (__bf16)tile[tx][ty0 + i * 8];
  }
}

__global__ __launch_bounds__(256) void prologue_kernel(const float* __restrict__ hs,
                                                       __bf16* __restrict__ Xb,
                                                       const float* __restrict__ Wq, __bf16* __restrict__ Wqt,
                                                       const float* __restrict__ Wk, __bf16* __restrict__ Wkt,
                                                       const float* __restrict__ Wv, __bf16* __restrict__ Wvt,
                                                       const float* __restrict__ Wo, __bf16* __restrict__ Wot) {
  __shared__ float tile[32][33];
  int id = blockIdx.x;
  if (id < 28672) {
    // convert: 28672*256 == 8192*3584/4 exactly (no bounds check needed)
    size_t i = (size_t)id * 256 + threadIdx.x;
    f32x4 v = *(const f32x4*)(hs + i * 4);
    bf16x4 o;
    #pragma unroll
    for (int j = 0; j < 4; ++j) o[j] = (__bf16)v[j];
    *(bf16x4*)(Xb + i * 4) = o;
  } else if (id < 43008) {         // Wq: dim3(128,112)
    int t = id - 28672;
    transpose_body(Wq, Wqt, 3584, 4096, t % 128, t / 128, tile);
  } else if (id < 50176) {         // Wk: dim3(64,112)
    int t = id - 43008;
    transpose_body(Wk, Wkt, 3584, 2048, t % 64, t / 64, tile);
  } else if (id < 57344) {         // Wv: dim3(64,112)
    int t = id - 50176;
    transpose_body(Wv, Wvt, 3584, 2048, t % 64, t / 64, tile);
  } else {                          // Wo: dim3(112,128)
    int t = id - 57344;
    transpose_body(Wo, Wot, 4096, 3584, t % 112, t / 112, tile);
  }
}

// ---------------- 256x256 pipelined bf16 GEMM (FROZEN R5 schedule, 45% MfmaUtil) ------
// MODE epilogues: 0=plain, 1=RoPE fused, 2=V permuted.

template<bool REMAP>
__device__ __forceinline__ void stage_q(__bf16* region, int qrow, const __bf16* src,
                                        int K, int w, int l) {
  int s = qrow + w * 8 + (l >> 3);
  int gr = REMAP ? (((s >> 5) << 4) | (s & 15) | (((s >> 4) & 1) << 7)) : s;
  async_copy16(region + (size_t)(qrow + w * 8) * 64,
               src + (size_t)gr * K + (((l & 7) ^ (s & 7)) << 3));
}

template<bool LATE, bool EARLY, bool NEXT, int G2, int G3, bool BMAP>
__device__ __forceinline__ void tile_body(__bf16* smem,
                                          const __bf16* Apan, const __bf16* Bpan,
                                          int K, int tau, int wm, int wn,
                                          int lo, int hi, int w, int l,
                                          bf16x8 (&aA)[4], bf16x8 (&aB)[4],
                                          bf16x8 (&bA)[4], bf16x8 (&bB)[4],
                                          f32x4 (&acc)[8][4]) {
  const int buf = tau & 1;
  __bf16* Ab = smem + buf * 32768;
  __bf16* Bb = Ab + 16384;
  __bf16* An = smem + (buf ^ 1) * 32768;
  __bf16* Bn = An + 16384;

  // ---- block0: R1 = aB <- a(h1,k0)[buf]; S0 = LATE; lgkm(4) drains R0; M0 = aA*bA
  #pragma unroll
  for (int t = 0; t < 4; ++t) {
    int ra = wm * 128 + 64 + t * 16 + lo;
    aB[t] = *(const bf16x8*)(Ab + (size_t)ra * 64 + ((hi ^ (ra & 7)) << 3));
  }
  if constexpr (LATE) {
    const __bf16* Ap1 = Apan + (size_t)(tau + 1) * 64;
    stage_q<false>(An, 64,  Ap1, K, w, l);   // A q1
    stage_q<false>(An, 192, Ap1, K, w, l);   // A q3
  }
  LGKM(4);
  __builtin_amdgcn_s_setprio(1);
  #pragma unroll
  for (int mt = 0; mt < 4; ++mt)
    #pragma unroll
    for (int nt = 0; nt < 4; ++nt)
      acc[mt][nt] = MFMA16(aA[mt], bA[nt], acc[mt][nt]);
  __builtin_amdgcn_s_setprio(0);
  BARRIER;

  // ---- block1: R2 = aA <- a(h0,k1), bB <- b(k1) [buf]; lgkm(8) drains R1; M1 = aB*bA
  #pragma unroll
  for (int t = 0; t < 4; ++t) {
    int ra = wm * 128 + t * 16 + lo;
    aA[t] = *(const bf16x8*)(Ab + (size_t)ra * 64 + (((4 + hi) ^ (ra & 7)) << 3));
  }
  #pragma unroll
  for (int t = 0; t < 4; ++t) {
    int rb = wn * 64 + t * 16 + lo;
    bB[t] = *(const bf16x8*)(Bb + (size_t)rb * 64 + (((4 + hi) ^ (rb & 7)) << 3));
  }
  LGKM(8);
  __builtin_amdgcn_s_setprio(1);
  #pragma unroll
  for (int mt = 0; mt < 4; ++mt)
    #pragma unroll
    for (int nt = 0; nt < 4; ++nt)
      acc[4 + mt][nt] = MFMA16(aB[mt], bA[nt], acc[4 + mt][nt]);
  __builtin_amdgcn_s_setprio(0);
  BARRIER;

  // ---- block2: R3 = aB <- a(h1,k1)[buf]; lgkm(4) drains R2; M2 = aA*bB;
  //      G2 gate BEFORE bar2 (cross-wave: EARLY(tau+1) landed for everyone)
  #pragma unroll
  for (int t = 0; t < 4; ++t) {
    int ra = wm * 128 + 64 + t * 16 + lo;
    aB[t] = *(const bf16x8*)(Ab + (size_t)ra * 64 + (((4 + hi) ^ (ra & 7)) << 3));
  }
  LGKM(4);
  __builtin_amdgcn_s_setprio(1);
  #pragma unroll
  for (int mt = 0; mt < 4; ++mt)
    #pragma unroll
    for (int nt = 0; nt < 4; ++nt)
      acc[mt][nt] = MFMA16(aA[mt], bB[nt], acc[mt][nt]);
  __builtin_amdgcn_s_setprio(0);
  if constexpr (G2 >= 0) vmcnt_gate<G2>();
  BARRIER;

  // ---- block3: R0' = aA <- a(h0,k0), bA <- b(k0) [nbuf] (NEXT); S3 = EARLY(tau+2 -> buf);
  //      lgkm(8|0) drains R3; M3 = aB*bB; G3 gate BEFORE bar3 (LATE landed for everyone)
  if constexpr (NEXT) {
    #pragma unroll
    for (int t = 0; t < 4; ++t) {
      int ra = wm * 128 + t * 16 + lo;
      aA[t] = *(const bf16x8*)(An + (size_t)ra * 64 + ((hi ^ (ra & 7)) << 3));
    }
    #pragma unroll
    for (int t = 0; t < 4; ++t) {
      int rb = wn * 64 + t * 16 + lo;
      bA[t] = *(const bf16x8*)(Bn + (size_t)rb * 64 + ((hi ^ (rb & 7)) << 3));
    }
  }
  if constexpr (EARLY) {
    const __bf16* Ap2 = Apan + (size_t)(tau + 2) * 64;
    const __bf16* Bp2 = Bpan + (size_t)(tau + 2) * 64;
    stage_q<false>(Ab, 0,   Ap2, K, w, l);   // A q0
    stage_q<false>(Ab, 128, Ap2, K, w, l);   // A q2
    stage_q<BMAP>(Bb, 0,   Bp2, K, w, l);    // B q0
    stage_q<BMAP>(Bb, 64,  Bp2, K, w, l);    // B q1
    stage_q<BMAP>(Bb, 128, Bp2, K, w, l);    // B q2
    stage_q<BMAP>(Bb, 192, Bp2, K, w, l);    // B q3
  }
  if constexpr (NEXT) LGKM(8); else LGKM(0);
  __builtin_amdgcn_s_setprio(1);
  #pragma unroll
  for (int mt = 0; mt < 4; ++mt)
    #pragma unroll
    for (int nt = 0; nt < 4; ++nt)
      acc[4 + mt][nt] = MFMA16(aB[mt], bB[nt], acc[4 + mt][nt]);
  __builtin_amdgcn_s_setprio(0);
  if constexpr (G3 >= 0) vmcnt_gate<G3>();
  BARRIER;
}

template <typename CT, int MODE>
__device__ __forceinline__ void gemm_body(const __bf16* __restrict__ A,
                                          const __bf16* __restrict__ Bt,
                                          CT* __restrict__ C, int M, int N, int K,
                                          const float* __restrict__ cosT,
                                          const float* __restrict__ sinT,
                                          int Hh, __bf16* smem, int m0, int n0) {
  constexpr bool BMAP = (MODE == 1);

  const int tid = threadIdx.x;
  const int l = tid & 63, w = tid >> 6;
  const int lo = l & 15, hi = l >> 4;
  const int wm = w >> 2, wn = w & 3;

  const __bf16* Apan = A + (size_t)m0 * K;
  const __bf16* Bpan = Bt + (size_t)n0 * K;

  f32x4 acc[8][4] = {};
  bf16x8 aA[4], aB[4], bA[4], bB[4];

  // prologue: stage tile0 (8 quanta) + tile1 (EARLY order first, LATE last);
  // vmcnt(8) = tile0 landed (per-wave) BEFORE barrier -> cross-wave visible after.
  stage_q<false>(smem,          0,   Apan, K, w, l);
  stage_q<false>(smem,          128, Apan, K, w, l);
  stage_q<BMAP>(smem + 16384,  0,   Bpan, K, w, l);
  stage_q<BMAP>(smem + 16384,  64,  Bpan, K, w, l);
  stage_q<BMAP>(smem + 16384,  128, Bpan, K, w, l);
  stage_q<BMAP>(smem + 16384,  192, Bpan, K, w, l);
  stage_q<false>(smem,          64,  Apan, K, w, l);
  stage_q<false>(smem,          192, Apan, K, w, l);
  stage_q<false>(smem + 32768,  0,   Apan + 64, K, w, l);
  stage_q<false>(smem + 32768,  128, Apan + 64, K, w, l);
  stage_q<BMAP>(smem + 49152,  0,   Bpan + 64, K, w, l);
  stage_q<BMAP>(smem + 49152,  64,  Bpan + 64, K, w, l);
  stage_q<BMAP>(smem + 49152,  128, Bpan + 64, K, w, l);
  stage_q<BMAP>(smem + 49152,  192, Bpan + 64, K, w, l);
  stage_q<false>(smem + 32768,  64,  Apan + 64, K, w, l);
  stage_q<false>(smem + 32768,  192, Apan + 64, K, w, l);
  vmcnt_gate<8>();
  BARRIER;

  #pragma unroll
  for (int t = 0; t < 4; ++t) {
    int ra = wm * 128 + t * 16 + lo;
    aA[t] = *(const bf16x8*)(smem + (size_t)ra * 64 + ((hi ^ (ra & 7)) << 3));
  }
  #pragma unroll
  for (int t = 0; t < 4; ++t) {
    int rb = wn * 64 + t * 16 + lo;
    bA[t] = *(const bf16x8*)(smem + 16384 + (size_t)rb * 64 + ((hi ^ (rb & 7)) << 3));
  }

  const int T = K >> 6;
  tile_body<false, true,  true,  2,  6, BMAP>(smem, Apan, Bpan, K, 0,     wm, wn, lo, hi, w, l, aA, aB, bA, bB, acc);
  for (int tau = 1; tau < T - 2; ++tau)
    tile_body<true, true,  true,  2,  6, BMAP>(smem, Apan, Bpan, K, tau,   wm, wn, lo, hi, w, l, aA, aB, bA, bB, acc);
  tile_body<true,  false, true,  2,  0, BMAP>(smem, Apan, Bpan, K, T - 2, wm, wn, lo, hi, w, l, aA, aB, bA, bB, acc);
  tile_body<false, false, false, -1, -1, BMAP>(smem, Apan, Bpan, K, T - 1, wm, wn, lo, hi, w, l, aA, aB, bA, bB, acc);

  if constexpr (MODE == 0) {
    // plain row-major C
    #pragma unroll
    for (int mt = 0; mt < 8; ++mt)
      #pragma unroll
      for (int nt = 0; nt < 4; ++nt) {
        int col = n0 + wn * 64 + nt * 16 + lo;
        #pragma unroll
        for (int r = 0; r < 4; ++r) {
          int row = m0 + wm * 128 + mt * 16 + 4 * hi + r;
          C[(size_t)row * N + col] = (CT)acc[mt][nt][r];
        }
      }
  } else if constexpr (MODE == 2) {
    // V: store to (b, kv, s, d); n-block == one KV head
    const int kv = n0 >> 8;
    #pragma unroll
    for (int mt = 0; mt < 8; ++mt)
      #pragma unroll
      for (int nt = 0; nt < 4; ++nt) {
        int col = wn * 64 + nt * 16 + lo;
        #pragma unroll
        for (int r = 0; r < 4; ++r) {
          int row = m0 + wm * 128 + mt * 16 + 4 * hi + r;
          int bb = row >> 12, sdx = row & 4095;
          C[(((size_t)(bb * Hh + kv)) * 4096 + sdx) * 256 + col] = (CT)acc[mt][nt][r];
        }
      }
  } else {
    // MODE 1: fused RoPE + store to (b, h, s, d). acc cols are colmap-permuted:
    // pair (nt, nt+1) = (d, d+128) with d = (2*wn + (nt>>1))*16 + lo.
    const int hq = n0 >> 8;
    #pragma unroll
    for (int mt = 0; mt < 8; ++mt)
      #pragma unroll
      for (int ntp = 0; ntp < 4; ntp += 2) {
        int d = (2 * wn + (ntp >> 1)) * 16 + lo;
        #pragma unroll
        for (int r = 0; r < 4; ++r) {
          int row = m0 + wm * 128 + mt * 16 + 4 * hi + r;
          int bb = row >> 12, sdx = row & 4095;
          float cc = cosT[(size_t)sdx * 128 + d];
          float ss = sinT[(size_t)sdx * 128 + d];
          float x1 = acc[mt][ntp][r], x2 = acc[mt][ntp + 1][r];
          size_t base = (((size_t)(bb * Hh + hq)) * 4096 + sdx) * 256;
          C[base + d]       = (CT)(x1 * cc - x2 * ss);
          C[base + d + 128] = (CT)(x1 * ss + x2 * cc);
        }
      }
  }
}

template <typename CT, int MODE>
__global__ __launch_bounds__(512, 2) void gemm256_kernel(const __bf16* __restrict__ A,
                                                         const __bf16* __restrict__ Bt,
                                                         CT* __restrict__ C, int M, int N, int K,
                                                         const float* __restrict__ cosT,
                                                         const float* __restrict__ sinT,
                                                         int Hh) {
  extern __shared__ __bf16 smem[];
  // XCD-bijective block swizzle (all grids have nwg % 8 == 0)
  const int gx = gridDim.x;
  const int nwg = gx * gridDim.y;
  const int wg = blockIdx.y * gx + blockIdx.x;
  const int qq = nwg >> 3;
  const int id2 = (wg & 7) * qq + (wg >> 3);
  const int m0 = (id2 / gx) * 256, n0 = (id2 % gx) * 256;
  gemm_body<CT, MODE>(A, Bt, C, M, N, K, cosT, sinT, Hh, smem, m0, n0);
}

// merged Q+K+V GEMM (R15): 1-D grid of 1024. [0,512)=Q (gx=16,nwg=512),
// [512,768)=K (gx=8,nwg=256), [768,1024)=V. Sub-range offsets are multiples of 8
// -> per-sub-launch XCD alignment identical to the original separate launches;
// per-half swizzles bit-identical. Kills one boundary + overlaps Q tail with K start.
__global__ __launch_bounds__(512, 2) void gemm256qkv_kernel(const __bf16* __restrict__ A,
                                                            const __bf16* __restrict__ Bq,
                                                            __bf16* __restrict__ Cq,
                                                            const __bf16* __restrict__ Bk,
                                                            __bf16* __restrict__ Ck,
                                                            const __bf16* __restrict__ Bv,
                                                            __bf16* __restrict__ Cv,
                                                            int M, int K,
                                                            const float* __restrict__ cosT,
                                                            const float* __restrict__ sinT) {
  extern __shared__ __bf16 smem[];
  const int id = blockIdx.x;
  if (id < 512) {
    const int gx = 16, wg = id, qq = 512 >> 3;
    const int id2 = (wg & 7) * qq + (wg >> 3);
    const int m0 = (id2 / gx) * 256, n0 = (id2 % gx) * 256;
    gemm_body<__bf16, 1>(A, Bq, Cq, M, 4096, K, cosT, sinT, 16, smem, m0, n0);
  } else if (id < 768) {
    const int gx = 8, wg = id - 512, qq = 256 >> 3;
    const int id2 = (wg & 7) * qq + (wg >> 3);
    const int m0 = (id2 / gx) * 256, n0 = (id2 % gx) * 256;
    gemm_body<__bf16, 1>(A, Bk, Ck, M, 2048, K, cosT, sinT, 8, smem, m0, n0);
  } else {
    const int gx = 8, wg = id - 768, qq = 256 >> 3;
    const int id2 = (wg & 7) * qq + (wg >> 3);
    const int m0 = (id2 / gx) * 256, n0 = (id2 % gx) * 256;
    gemm_body<__bf16, 2>(A, Bv, Cv, M, 2048, K, nullptr, nullptr, 8, smem, m0, n0);
  }
}

// ---------------- feature map (merged q+k: grid (32, 64); y>=32 = k path) -------------
__global__ __launch_bounds__(256) void fm_kernel(const __bf16* __restrict__ ropq,
                                                 const __bf16* __restrict__ ropk,
                                                 const float* __restrict__ fmq,
                                                 const float* __restrict__ fmk,
                                                 __bf16* __restrict__ outq,
                                                 __bf16* __restrict__ outk) {
  __shared__ __bf16 fmT[64][256];  // [f][d] swizzled: group' = (d>>3) ^ (f&7)
  const int half = blockIdx.y >> 5;
  const __bf16* rope = half ? ropk : ropq;
  const float* fm = half ? fmk : fmq;
  __bf16* out = half ? outk : outq;
  const int srcH = half ? 8 : 16;
  const float scale = half ? 1.0f : 0.08838834764831845f;

  int bh = blockIdx.y & 31;
  int h = bh & 15, b = bh >> 4;
  int s0 = blockIdx.x * 128;
  int tid = threadIdx.x, lane = tid & 63, wid = tid >> 6, hi = lane >> 4, lo = lane & 15;

  const float* fmh = fm + (size_t)h * 256 * 64;
  for (int i = tid; i < 256 * 64; i += 256) {
    int d = i >> 6, f = i & 63;
    fmT[f][(((d >> 3) ^ (f & 7)) << 3) | (d & 7)] = (__bf16)fmh[i];
  }
  __syncthreads();

  int srch = (srcH == 16) ? h : (h >> 1);
  const __bf16* abase = rope + ((size_t)(b * srcH + srch) * 4096 + s0 + 32 * wid) * 256;
  f32x4 acc[2][4] = {};
  for (int kk = 0; kk < 256; kk += 32) {
    bf16x8 a[2], bf[4];
    #pragma unroll
    for (int mt = 0; mt < 2; ++mt)
      a[mt] = *(const bf16x8*)(abase + (size_t)(16 * mt + lo) * 256 + kk + 8 * hi);
    const int G = (kk >> 3) + hi;
    #pragma unroll
    for (int nt = 0; nt < 4; ++nt) {
      int f = 16 * nt + lo;
      bf[nt] = *(const bf16x8*)&fmT[f][(G ^ (f & 7)) << 3];
    }
    #pragma unroll
    for (int mt = 0; mt < 2; ++mt)
      #pragma unroll
      for (int nt = 0; nt < 4; ++nt)
        acc[mt][nt] = MFMA16(a[mt], bf[nt], acc[mt][nt]);
  }

  size_t obase = ((size_t)(b * 16 + h) * 4096 + s0 + 32 * wid);
  #pragma unroll
  for (int mt = 0; mt < 2; ++mt) {
    #pragma unroll
    for (int r = 0; r < 4; ++r) {
      float z0 = acc[mt][0][r], z1 = acc[mt][1][r], z2 = acc[mt][2][r], z3 = acc[mt][3][r];
      float mx = fmaxf(fmaxf(z0, z1), fmaxf(z2, z3));
      float mn = fminf(fminf(z0, z1), fminf(z2, z3));
      #pragma unroll
      for (int off = 1; off < 16; off <<= 1) {
        mx = fmaxf(mx, __shfl_xor(mx, off));
        mn = fminf(mn, __shfl_xor(mn, off));
      }
      float ep0 = __expf(z0 - mx), ep1 = __expf(z1 - mx), ep2 = __expf(z2 - mx), ep3 = __expf(z3 - mx);
      float en0 = __expf(mn - z0), en1 = __expf(mn - z1), en2 = __expf(mn - z2), en3 = __expf(mn - z3);
      float sp = ep0 + ep1 + ep2 + ep3, sn = en0 + en1 + en2 + en3;
      #pragma unroll
      for (int off = 1; off < 16; off <<= 1) {
        sp += __shfl_xor(sp, off);
        sn += __shfl_xor(sn, off);
      }
      float rp = scale / sp, rn = scale / sn;
      int row = 16 * mt + 4 * hi + r;
      __bf16* op = out + (obase + row) * 128;
      op[0  + lo] = (__bf16)(ep0 * rp);  op[16 + lo] = (__bf16)(ep1 * rp);
      op[32 + lo] = (__bf16)(ep2 * rp);  op[48 + lo] = (__bf16)(ep3 * rp);
      op[64 + lo] = (__bf16)(en0 * rn);  op[80 + lo] = (__bf16)(en1 * rn);
      op[96 + lo] = (__bf16)(en2 * rn);  op[112 + lo] = (__bf16)(en3 * rn);
    }
  }
}

// ---------------- chunked linear attention (software-pipelined; best measured) ----------
// XCD swizzle (R7): dv-siblings share an XCD -> q/k head-slices L2-local.
// Pipeline (R8): double-buffered K/V, prefetch n+1 at top of n, light syncs.
__global__ __launch_bounds__(256) void attn_kernel(const __bf16* __restrict__ qf,
                                                   const __bf16* __restrict__ kf,
                                                   const __bf16* __restrict__ vp,
                                                   __bf16* __restrict__ o) {
  __shared__ __bf16 k_s[2][64][128];
  __shared__ __bf16 vT_s[2][32][64];
  __shared__ __bf16 sc_s[64][64];
  __shared__ __bf16 STb[32][128];

  int bid = blockIdx.x;
  int g   = ((bid >> 6) << 3) | (bid & 7);   // 0..31 = b*16 + h
  int dvb = (bid >> 3) & 7;
  int h = g & 15, b = g >> 4;
  int dv0 = dvb * 32;
  int tid = threadIdx.x, lane = tid & 63, wid = tid >> 6, hi = lane >> 4, lo = lane & 15;

  const __bf16* qh = qf + ((size_t)(b * 16 + h)) * 4096 * 128;
  const __bf16* kh = kf + ((size_t)(b * 16 + h)) * 4096 * 128;
  const __bf16* vh = vp + ((size_t)(b * 8 + (h >> 1))) * 4096 * 256 + dv0;
  __bf16* oh = o + ((size_t)b * 4096) * 4096 + h * 256 + dv0;

  {
    unsigned int* z = (unsigned int*)&STb[0][0];
    for (int i = tid; i < 2048; i += 256) z[i] = 0u;
  }
  f32x4 st[2][2] = {};

  const int vc = tid >> 2, vd8 = (tid & 3) * 8;
  bf16x8 aqN[4], aqC[4], vvN;

  // ---- prologue: K(0)->buf0, V(0)->reg, q(0)->reg; vT_s[0] write waits vv(0)
  // (FIFO => K(0) drained per-wave); lgkm(0)+barrier -> cross-wave visible.
  #pragma unroll
  for (int i = 0; i < 4; ++i) {
    int rb = (wid * 4 + i) * 4;
    int r = rb + (lane >> 4);
    int Glog = (lane & 15) ^ (r & 7);
    async_copy16(&k_s[0][rb][0], kh + (size_t)r * 128 + Glog * 8);
  }
  __builtin_amdgcn_sched_barrier(0);
  vvN = *(const bf16x8*)(vh + (size_t)vc * 256 + vd8);
  __builtin_amdgcn_sched_barrier(0);
  #pragma unroll
  for (int kq = 0; kq < 4; ++kq)
    aqN[kq] = *(const bf16x8*)(qh + (size_t)(16 * wid + lo) * 128 + 32 * kq + 8 * hi);
  __builtin_amdgcn_sched_barrier(0);
  #pragma unroll
  for (int j = 0; j < 8; ++j) {
    int dv = vd8 + j;
    vT_s[0][dv][(((vc >> 3) ^ (dv & 7)) << 3) | (vc & 7)] = vvN[j];
  }
  LGKM(0);
  BARRIER;

  for (int n = 0; n < 64; ++n) {
    const int buf = n & 1;
    const int s0 = n * 64;

    // consume q(n) (compiler waits the n-issued loads here), then prefetch n+1
    #pragma unroll
    for (int kq = 0; kq < 4; ++kq) aqC[kq] = aqN[kq];

    if (n < 63) {
      const int s1 = s0 + 64;
      #pragma unroll
      for (int i = 0; i < 4; ++i) {
        int rb = (wid * 4 + i) * 4;
        int r = rb + (lane >> 4);
        int Glog = (lane & 15) ^ (r & 7);
        async_copy16(&k_s[buf ^ 1][rb][0], kh + (size_t)(s1 + r) * 128 + Glog * 8);
      }
      __builtin_amdgcn_sched_barrier(0);
      vvN = *(const bf16x8*)(vh + (size_t)(s1 + vc) * 256 + vd8);
      __builtin_amdgcn_sched_barrier(0);
      #pragma unroll
      for (int kq = 0; kq < 4; ++kq)
        aqN[kq] = *(const bf16x8*)(qh + (size_t)(s1 + 16 * wid + lo) * 128 + 32 * kq + 8 * hi);
      __builtin_amdgcn_sched_barrier(0);
    }

    // ---- compute on buf: inter (q @ STb) + scores (q @ k)
    f32x4 acc_o[2] = {}, sacc[4] = {};
    #pragma unroll
    for (int nt = 0; nt < 2; ++nt)
      #pragma unroll
      for (int kq = 0; kq < 4; ++kq) {
        int rr = 16 * nt + lo, G = 4 * kq + hi;
        bf16x8 bf = *(const bf16x8*)&STb[rr][(G ^ (rr & 7)) << 3];
        acc_o[nt] = MFMA16(aqC[kq], bf, acc_o[nt]);
      }
    #pragma unroll
    for (int nt = 0; nt < 4; ++nt)
      #pragma unroll
      for (int kq = 0; kq < 4; ++kq) {
        int rr = 16 * nt + lo, G = 4 * kq + hi;
        bf16x8 bf = *(const bf16x8*)&k_s[buf][rr][(G ^ (rr & 7)) << 3];
        sacc[nt] = MFMA16(aqC[kq], bf, sacc[nt]);
      }
    // causal mask -> sc_s (wave-private 16-row band; intra-wave fence suffices)
    #pragma unroll
    for (int nt = 0; nt < 4; ++nt)
      #pragma unroll
      for (int r = 0; r < 4; ++r) {
        int c = 16 * wid + 4 * hi + r;
        int cp = 16 * nt + lo;
        float v = (cp <= c) ? sacc[nt][r] : 0.0f;
        sc_s[c][(((cp >> 3) ^ (c & 7)) << 3) | (cp & 7)] = (__bf16)v;
      }
    asm volatile("" ::: "memory");
    // intra: sc @ vT
    #pragma unroll
    for (int nt = 0; nt < 2; ++nt)
      #pragma unroll
      for (int kq = 0; kq < 2; ++kq) {
        int rA = 16 * wid + lo, GA = 4 * kq + hi;
        bf16x8 af = *(const bf16x8*)&sc_s[rA][(GA ^ (rA & 7)) << 3];
        int rB = 16 * nt + lo;
        bf16x8 bf = *(const bf16x8*)&vT_s[buf][rB][(GA ^ (rB & 7)) << 3];
        acc_o[nt] = MFMA16(af, bf, acc_o[nt]);
      }
    #pragma unroll
    for (int nt = 0; nt < 2; ++nt)
      #pragma unroll
      for (int r = 0; r < 4; ++r) {
        int c = 16 * wid + 4 * hi + r;
        oh[(size_t)(s0 + c) * 4096 + 16 * nt + lo] = (__bf16)acc_o[nt][r];
      }

    if (n == 63) break;   // ST update is dead on the last chunk

    BARRIER;  // mid: raw barrier (all pre-barrier LDS reads register-consumed)

    // ---- ST update: st += v^T @ k  (bu rebuilt from k_s[buf])
    bf16x8 bu[2][2];
    #pragma unroll
    for (int q = 0; q < 2; ++q) {
      int dk = 16 * (2 * wid + q) + lo;
      #pragma unroll
      for (int kq = 0; kq < 2; ++kq) {
        bf16x8 tmp;
        #pragma unroll
        for (int j = 0; j < 8; ++j) {
          int c = 32 * kq + 8 * hi + j;
          tmp[j] = k_s[buf][c][(((dk >> 3) ^ (c & 7)) << 3) | (dk & 7)];
        }
        bu[q][kq] = tmp;
      }
    }
    #pragma unroll
    for (int mt = 0; mt < 2; ++mt)
      #pragma unroll
      for (int kq = 0; kq < 2; ++kq) {
        int rA = 16 * mt + lo, GA = 4 * kq + hi;
        bf16x8 av = *(const bf16x8*)&vT_s[buf][rA][(GA ^ (rA & 7)) << 3];
        #pragma unroll
        for (int q = 0; q < 2; ++q)
          st[mt][q] = MFMA16(av, bu[q][kq], st[mt][q]);
      }
    #pragma unroll
    for (int mt = 0; mt < 2; ++mt)
      #pragma unroll
      for (int q = 0; q < 2; ++q) {
        int dk = 16 * (2 * wid + q) + lo;
        #pragma unroll
        for (int r = 0; r < 4; ++r) {
          int dvr = 16 * mt + 4 * hi + r;
          STb[dvr][(((dk >> 3) ^ (dvr & 7)) << 3) | (dk & 7)] = (__bf16)st[mt][q][r];
        }
      }
    // vT_s[buf^1] <- vv(n+1): compiler waits vv(n+1) => K(n+1) (older) drained
    #pragma unroll
    for (int j = 0; j < 8; ++j) {
      int dv = vd8 + j;
      vT_s[buf ^ 1][dv][(((vc >> 3) ^ (dv & 7)) << 3) | (vc & 7)] = vvN[j];
    }
    LGKM(0);   // ds_writes (STb, vT_s) visible cross-wave after barrier
    BARRIER;
  }
}

// ---------------- launch ----------------
extern "C" void kernel_launch(void* const* d_in, const int* in_sizes, int n_in,
                              void* d_out, int out_size, void* d_ws, size_t ws_size,
                              hipStream_t stream) {
  (void)in_sizes; (void)n_in; (void)out_size; (void)ws_size;
  const float* hs   = (const float*)d_in[0];
  const float* cosT = (const float*)d_in[1];
  const float* sinT = (const float*)d_in[2];
  const float* Wq   = (const float*)d_in[3];
  const float* Wk   = (const float*)d_in[4];
  const float* Wv   = (const float*)d_in[5];
  const float* Wo   = (const float*)d_in[6];
  const float* fmq  = (const float*)d_in[7];
  const float* fmk  = (const float*)d_in[8];
  float* out = (float*)d_out;
  char* ws = (char*)d_ws;

  hipFuncSetAttribute((const void*)gemm256_kernel<float, 0>,
                      hipFuncAttributeMaxDynamicSharedMemorySize, 131072);
  hipFuncSetAttribute((const void*)gemm256qkv_kernel,
                      hipFuncAttributeMaxDynamicSharedMemorySize, 131072);

  const size_t MB = 1024ull * 1024ull;
  __bf16* Xb   = (__bf16*)(ws + 0);
  __bf16* qfb  = (__bf16*)(ws + 0);
  __bf16* kfb  = (__bf16*)(ws + 34 * MB);
  __bf16* Wqt  = (__bf16*)(ws + 70 * MB);
  __bf16* ob   = (__bf16*)(ws + 70 * MB);
  __bf16* Wkt  = (__bf16*)(ws + 104 * MB);
  __bf16* Wvt  = (__bf16*)(ws + 119 * MB);
  __bf16* Wot  = (__bf16*)(ws + 140 * MB);
  __bf16* ropq = (__bf16*)(ws + 170 * MB);
  __bf16* ropk = (__bf16*)(ws + 238 * MB);
  __bf16* vpb  = (__bf16*)(ws + 272 * MB);

  prologue_kernel<<<71680, 256, 0, stream>>>(hs, Xb, Wq, Wqt, Wk, Wkt, Wv, Wvt, Wo, Wot);

  gemm256qkv_kernel<<<1024, 512, 131072, stream>>>(
      Xb, Wqt, ropq, Wkt, ropk, Wvt, vpb, 8192, 3584, cosT, sinT);

  fm_kernel<<<dim3(32, 64), 256, 0, stream>>>(ropq, ropk, fmq, fmk, qfb, kfb);

  attn_kernel<<<256, 256, 0, stream>>>(qfb, kfb, vpb, ob);

  gemm256_kernel<float, 0><<<dim3(14, 32), 512, 131072, stream>>>(
      ob, Wot, out, 8192, 3584, 4096, nullptr, nullptr, 0);
}

// Round 16
// 898.736 us; speedup vs baseline: 1.0610x; 1.0038x over previous
//
#include <hip/hip_runtime.h>

// ---------------- types / helpers ----------------
typedef float  f32x4  __attribute__((ext_vector_type(4)));
typedef __bf16 bf16x4 __attribute__((ext_vector_type(4)));
typedef __bf16 bf16x8 __attribute__((ext_vector_type(8)));

#define MFMA16(a,b,c) __builtin_amdgcn_mfma_f32_16x16x32_bf16((a),(b),(c),0,0,0)

__device__ __forceinline__ void async_copy16(void* lds, const void* gmem) {
  __builtin_amdgcn_global_load_lds(
      (const __attribute__((address_space(1))) void*)gmem,
      (__attribute__((address_space(3))) void*)lds, 16, 0, 0);
}

template<int N> __device__ __forceinline__ void vmcnt_gate() {
  if constexpr (N == 8) asm volatile("s_waitcnt vmcnt(8)" ::: "memory");
  else if constexpr (N == 6) asm volatile("s_waitcnt vmcnt(6)" ::: "memory");
  else if constexpr (N == 4) asm volatile("s_waitcnt vmcnt(4)" ::: "memory");
  else if constexpr (N == 2) asm volatile("s_waitcnt vmcnt(2)" ::: "memory");
  else if constexpr (N == 0) asm volatile("s_waitcnt vmcnt(0)" ::: "memory");
  __builtin_amdgcn_sched_barrier(0);
}

// counted lgkm wait: drains all ds_reads OLDER than the N just issued (rule #18 fences)
#define LGKM(N) do { __builtin_amdgcn_sched_barrier(0); \
                     asm volatile("s_waitcnt lgkmcnt(" #N ")" ::: "memory"); \
                     __builtin_amdgcn_sched_barrier(0); } while (0)

#define BARRIER do { __builtin_amdgcn_sched_barrier(0); \
                     __builtin_amdgcn_s_barrier(); \
                     __builtin_amdgcn_sched_barrier(0); } while (0)

// ---------------- merged prologue: convert + 4 weight transposes ----------------
// All 5 sub-kernels independent (disjoint reads/writes); merging kills 4 launch
// boundaries (each = tail drain + ~3-5us CP turnaround). Block-uniform branches.

__device__ __forceinline__ void transpose_body(const float* __restrict__ in,
                                               __bf16* __restrict__ out, int R, int C,
                                               int bx, int by, float (&tile)[32][33]) {
  int tx = threadIdx.x & 31, ty0 = threadIdx.x >> 5;
  #pragma unroll
  for (int i = 0; i < 4; ++i) {
    int r = by * 32 + ty0 + i * 8;
    tile[ty0 + i * 8][tx] = in[(size_t)r * C + bx * 32 + tx];
  }
  __syncthreads();
  #pragma unroll
  for (int i = 0; i < 4; ++i) {
    int c = bx * 32 + ty0 + i * 8;
    out[(size_t)c * R + by * 32 + tx] = (__bf16)tile[tx][ty0 + i * 8];
  }
}

__global__ __launch_bounds__(256) void prologue_kernel(const float* __restrict__ hs,
                                                       __bf16* __restrict__ Xb,
                                                       const float* __restrict__ Wq, __bf16* __restrict__ Wqt,
                                                       const float* __restrict__ Wk, __bf16* __restrict__ Wkt,
                                                       const float* __restrict__ Wv, __bf16* __restrict__ Wvt,
                                                       const float* __restrict__ Wo, __bf16* __restrict__ Wot) {
  __shared__ float tile[32][33];
  int id = blockIdx.x;
  if (id < 28672) {
    // convert: 28672*256 == 8192*3584/4 exactly (no bounds check needed)
    size_t i = (size_t)id * 256 + threadIdx.x;
    f32x4 v = *(const f32x4*)(hs + i * 4);
    bf16x4 o;
    #pragma unroll
    for (int j = 0; j < 4; ++j) o[j] = (__bf16)v[j];
    *(bf16x4*)(Xb + i * 4) = o;
  } else if (id < 43008) {         // Wq: dim3(128,112)
    int t = id - 28672;
    transpose_body(Wq, Wqt, 3584, 4096, t % 128, t / 128, tile);
  } else if (id < 50176) {         // Wk: dim3(64,112)
    int t = id - 43008;
    transpose_body(Wk, Wkt, 3584, 2048, t % 64, t / 64, tile);
  } else if (id < 57344) {         // Wv: dim3(64,112)
    int t = id - 50176;
    transpose_body(Wv, Wvt, 3584, 2048, t % 64, t / 64, tile);
  } else {                          // Wo: dim3(112,128)
    int t = id - 57344;
    transpose_body(Wo, Wot, 4096, 3584, t % 112, t / 112, tile);
  }
}

// ---------------- 256x256 pipelined bf16 GEMM (FROZEN R5 schedule) ------
// MODE epilogues: 0=plain, 1=RoPE fused, 2=V permuted.

template<bool REMAP>
__device__ __forceinline__ void stage_q(__bf16* region, int qrow, const __bf16* src,
                                        int K, int w, int l) {
  int s = qrow + w * 8 + (l >> 3);
  int gr = REMAP ? (((s >> 5) << 4) | (s & 15) | (((s >> 4) & 1) << 7)) : s;
  async_copy16(region + (size_t)(qrow + w * 8) * 64,
               src + (size_t)gr * K + (((l & 7) ^ (s & 7)) << 3));
}

template<bool LATE, bool EARLY, bool NEXT, int G2, int G3, bool BMAP>
__device__ __forceinline__ void tile_body(__bf16* smem,
                                          const __bf16* Apan, const __bf16* Bpan,
                                          int K, int tau, int wm, int wn,
                                          int lo, int hi, int w, int l,
                                          bf16x8 (&aA)[4], bf16x8 (&aB)[4],
                                          bf16x8 (&bA)[4], bf16x8 (&bB)[4],
                                          f32x4 (&acc)[8][4]) {
  const int buf = tau & 1;
  __bf16* Ab = smem + buf * 32768;
  __bf16* Bb = Ab + 16384;
  __bf16* An = smem + (buf ^ 1) * 32768;
  __bf16* Bn = An + 16384;

  // ---- block0: R1 = aB <- a(h1,k0)[buf]; S0 = LATE; lgkm(4) drains R0; M0 = aA*bA
  #pragma unroll
  for (int t = 0; t < 4; ++t) {
    int ra = wm * 128 + 64 + t * 16 + lo;
    aB[t] = *(const bf16x8*)(Ab + (size_t)ra * 64 + ((hi ^ (ra & 7)) << 3));
  }
  if constexpr (LATE) {
    const __bf16* Ap1 = Apan + (size_t)(tau + 1) * 64;
    stage_q<false>(An, 64,  Ap1, K, w, l);   // A q1
    stage_q<false>(An, 192, Ap1, K, w, l);   // A q3
  }
  LGKM(4);
  __builtin_amdgcn_s_setprio(1);
  #pragma unroll
  for (int mt = 0; mt < 4; ++mt)
    #pragma unroll
    for (int nt = 0; nt < 4; ++nt)
      acc[mt][nt] = MFMA16(aA[mt], bA[nt], acc[mt][nt]);
  __builtin_amdgcn_s_setprio(0);
  BARRIER;

  // ---- block1: R2 = aA <- a(h0,k1), bB <- b(k1) [buf]; lgkm(8) drains R1; M1 = aB*bA
  #pragma unroll
  for (int t = 0; t < 4; ++t) {
    int ra = wm * 128 + t * 16 + lo;
    aA[t] = *(const bf16x8*)(Ab + (size_t)ra * 64 + (((4 + hi) ^ (ra & 7)) << 3));
  }
  #pragma unroll
  for (int t = 0; t < 4; ++t) {
    int rb = wn * 64 + t * 16 + lo;
    bB[t] = *(const bf16x8*)(Bb + (size_t)rb * 64 + (((4 + hi) ^ (rb & 7)) << 3));
  }
  LGKM(8);
  __builtin_amdgcn_s_setprio(1);
  #pragma unroll
  for (int mt = 0; mt < 4; ++mt)
    #pragma unroll
    for (int nt = 0; nt < 4; ++nt)
      acc[4 + mt][nt] = MFMA16(aB[mt], bA[nt], acc[4 + mt][nt]);
  __builtin_amdgcn_s_setprio(0);
  BARRIER;

  // ---- block2: R3 = aB <- a(h1,k1)[buf]; lgkm(4) drains R2; M2 = aA*bB;
  //      G2 gate BEFORE bar2 (cross-wave: EARLY(tau+1) landed for everyone)
  #pragma unroll
  for (int t = 0; t < 4; ++t) {
    int ra = wm * 128 + 64 + t * 16 + lo;
    aB[t] = *(const bf16x8*)(Ab + (size_t)ra * 64 + (((4 + hi) ^ (ra & 7)) << 3));
  }
  LGKM(4);
  __builtin_amdgcn_s_setprio(1);
  #pragma unroll
  for (int mt = 0; mt < 4; ++mt)
    #pragma unroll
    for (int nt = 0; nt < 4; ++nt)
      acc[mt][nt] = MFMA16(aA[mt], bB[nt], acc[mt][nt]);
  __builtin_amdgcn_s_setprio(0);
  if constexpr (G2 >= 0) vmcnt_gate<G2>();
  BARRIER;

  // ---- block3: R0' = aA <- a(h0,k0), bA <- b(k0) [nbuf] (NEXT); S3 = EARLY(tau+2 -> buf);
  //      lgkm(8|0) drains R3; M3 = aB*bB; G3 gate BEFORE bar3 (LATE landed for everyone)
  if constexpr (NEXT) {
    #pragma unroll
    for (int t = 0; t < 4; ++t) {
      int ra = wm * 128 + t * 16 + lo;
      aA[t] = *(const bf16x8*)(An + (size_t)ra * 64 + ((hi ^ (ra & 7)) << 3));
    }
    #pragma unroll
    for (int t = 0; t < 4; ++t) {
      int rb = wn * 64 + t * 16 + lo;
      bA[t] = *(const bf16x8*)(Bn + (size_t)rb * 64 + ((hi ^ (rb & 7)) << 3));
    }
  }
  if constexpr (EARLY) {
    const __bf16* Ap2 = Apan + (size_t)(tau + 2) * 64;
    const __bf16* Bp2 = Bpan + (size_t)(tau + 2) * 64;
    stage_q<false>(Ab, 0,   Ap2, K, w, l);   // A q0
    stage_q<false>(Ab, 128, Ap2, K, w, l);   // A q2
    stage_q<BMAP>(Bb, 0,   Bp2, K, w, l);    // B q0
    stage_q<BMAP>(Bb, 64,  Bp2, K, w, l);    // B q1
    stage_q<BMAP>(Bb, 128, Bp2, K, w, l);    // B q2
    stage_q<BMAP>(Bb, 192, Bp2, K, w, l);    // B q3
  }
  if constexpr (NEXT) LGKM(8); else LGKM(0);
  __builtin_amdgcn_s_setprio(1);
  #pragma unroll
  for (int mt = 0; mt < 4; ++mt)
    #pragma unroll
    for (int nt = 0; nt < 4; ++nt)
      acc[4 + mt][nt] = MFMA16(aB[mt], bB[nt], acc[4 + mt][nt]);
  __builtin_amdgcn_s_setprio(0);
  if constexpr (G3 >= 0) vmcnt_gate<G3>();
  BARRIER;
}

template <typename CT, int MODE>
__device__ __forceinline__ void gemm_body(const __bf16* __restrict__ A,
                                          const __bf16* __restrict__ Bt,
                                          CT* __restrict__ C, int M, int N, int K,
                                          const float* __restrict__ cosT,
                                          const float* __restrict__ sinT,
                                          int Hh, __bf16* smem, int m0, int n0) {
  constexpr bool BMAP = (MODE == 1);

  const int tid = threadIdx.x;
  const int l = tid & 63, w = tid >> 6;
  const int lo = l & 15, hi = l >> 4;
  const int wm = w >> 2, wn = w & 3;

  const __bf16* Apan = A + (size_t)m0 * K;
  const __bf16* Bpan = Bt + (size_t)n0 * K;

  f32x4 acc[8][4] = {};
  bf16x8 aA[4], aB[4], bA[4], bB[4];

  // prologue: stage tile0 (8 quanta) + tile1 (EARLY order first, LATE last);
  // vmcnt(8) = tile0 landed (per-wave) BEFORE barrier -> cross-wave visible after.
  stage_q<false>(smem,          0,   Apan, K, w, l);
  stage_q<false>(smem,          128, Apan, K, w, l);
  stage_q<BMAP>(smem + 16384,  0,   Bpan, K, w, l);
  stage_q<BMAP>(smem + 16384,  64,  Bpan, K, w, l);
  stage_q<BMAP>(smem + 16384,  128, Bpan, K, w, l);
  stage_q<BMAP>(smem + 16384,  192, Bpan, K, w, l);
  stage_q<false>(smem,          64,  Apan, K, w, l);
  stage_q<false>(smem,          192, Apan, K, w, l);
  stage_q<false>(smem + 32768,  0,   Apan + 64, K, w, l);
  stage_q<false>(smem + 32768,  128, Apan + 64, K, w, l);
  stage_q<BMAP>(smem + 49152,  0,   Bpan + 64, K, w, l);
  stage_q<BMAP>(smem + 49152,  64,  Bpan + 64, K, w, l);
  stage_q<BMAP>(smem + 49152,  128, Bpan + 64, K, w, l);
  stage_q<BMAP>(smem + 49152,  192, Bpan + 64, K, w, l);
  stage_q<false>(smem + 32768,  64,  Apan + 64, K, w, l);
  stage_q<false>(smem + 32768,  192, Apan + 64, K, w, l);
  vmcnt_gate<8>();
  BARRIER;

  #pragma unroll
  for (int t = 0; t < 4; ++t) {
    int ra = wm * 128 + t * 16 + lo;
    aA[t] = *(const bf16x8*)(smem + (size_t)ra * 64 + ((hi ^ (ra & 7)) << 3));
  }
  #pragma unroll
  for (int t = 0; t < 4; ++t) {
    int rb = wn * 64 + t * 16 + lo;
    bA[t] = *(const bf16x8*)(smem + 16384 + (size_t)rb * 64 + ((hi ^ (rb & 7)) << 3));
  }

  const int T = K >> 6;
  tile_body<false, true,  true,  2,  6, BMAP>(smem, Apan, Bpan, K, 0,     wm, wn, lo, hi, w, l, aA, aB, bA, bB, acc);
  for (int tau = 1; tau < T - 2; ++tau)
    tile_body<true, true,  true,  2,  6, BMAP>(smem, Apan, Bpan, K, tau,   wm, wn, lo, hi, w, l, aA, aB, bA, bB, acc);
  tile_body<true,  false, true,  2,  0, BMAP>(smem, Apan, Bpan, K, T - 2, wm, wn, lo, hi, w, l, aA, aB, bA, bB, acc);
  tile_body<false, false, false, -1, -1, BMAP>(smem, Apan, Bpan, K, T - 1, wm, wn, lo, hi, w, l, aA, aB, bA, bB, acc);

  if constexpr (MODE == 0) {
    // plain row-major C
    #pragma unroll
    for (int mt = 0; mt < 8; ++mt)
      #pragma unroll
      for (int nt = 0; nt < 4; ++nt) {
        int col = n0 + wn * 64 + nt * 16 + lo;
        #pragma unroll
        for (int r = 0; r < 4; ++r) {
          int row = m0 + wm * 128 + mt * 16 + 4 * hi + r;
          C[(size_t)row * N + col] = (CT)acc[mt][nt][r];
        }
      }
  } else if constexpr (MODE == 2) {
    // V: store to (b, kv, s, d); n-block == one KV head
    const int kv = n0 >> 8;
    #pragma unroll
    for (int mt = 0; mt < 8; ++mt)
      #pragma unroll
      for (int nt = 0; nt < 4; ++nt) {
        int col = wn * 64 + nt * 16 + lo;
        #pragma unroll
        for (int r = 0; r < 4; ++r) {
          int row = m0 + wm * 128 + mt * 16 + 4 * hi + r;
          int bb = row >> 12, sdx = row & 4095;
          C[(((size_t)(bb * Hh + kv)) * 4096 + sdx) * 256 + col] = (CT)acc[mt][nt][r];
        }
      }
  } else {
    // MODE 1: fused RoPE + store to (b, h, s, d). acc cols are colmap-permuted:
    // pair (nt, nt+1) = (d, d+128) with d = (2*wn + (nt>>1))*16 + lo.
    const int hq = n0 >> 8;
    #pragma unroll
    for (int mt = 0; mt < 8; ++mt)
      #pragma unroll
      for (int ntp = 0; ntp < 4; ntp += 2) {
        int d = (2 * wn + (ntp >> 1)) * 16 + lo;
        #pragma unroll
        for (int r = 0; r < 4; ++r) {
          int row = m0 + wm * 128 + mt * 16 + 4 * hi + r;
          int bb = row >> 12, sdx = row & 4095;
          float cc = cosT[(size_t)sdx * 128 + d];
          float ss = sinT[(size_t)sdx * 128 + d];
          float x1 = acc[mt][ntp][r], x2 = acc[mt][ntp + 1][r];
          size_t base = (((size_t)(bb * Hh + hq)) * 4096 + sdx) * 256;
          C[base + d]       = (CT)(x1 * cc - x2 * ss);
          C[base + d + 128] = (CT)(x1 * ss + x2 * cc);
        }
      }
  }
}

template <typename CT, int MODE>
__global__ __launch_bounds__(512, 2) void gemm256_kernel(const __bf16* __restrict__ A,
                                                         const __bf16* __restrict__ Bt,
                                                         CT* __restrict__ C, int M, int N, int K,
                                                         const float* __restrict__ cosT,
                                                         const float* __restrict__ sinT,
                                                         int Hh) {
  extern __shared__ __bf16 smem[];
  // XCD-bijective block swizzle (all grids have nwg % 8 == 0)
  const int gx = gridDim.x;
  const int nwg = gx * gridDim.y;
  const int wg = blockIdx.y * gx + blockIdx.x;
  const int qq = nwg >> 3;
  const int id2 = (wg & 7) * qq + (wg >> 3);
  const int m0 = (id2 / gx) * 256, n0 = (id2 % gx) * 256;
  gemm_body<CT, MODE>(A, Bt, C, M, N, K, cosT, sinT, Hh, smem, m0, n0);
}

// merged Q+K+V GEMM: 1-D grid of 1024. [0,512)=Q (gx=16,nwg=512),
// [512,768)=K (gx=8,nwg=256), [768,1024)=V. Sub-range offsets are multiples of 8
// -> per-sub-launch XCD alignment identical to the original separate launches.
// Measured: co-scheduled mixed-phase blocks raise MfmaUtil to 50.8% (best of session).
__global__ __launch_bounds__(512, 2) void gemm256qkv_kernel(const __bf16* __restrict__ A,
                                                            const __bf16* __restrict__ Bq,
                                                            __bf16* __restrict__ Cq,
                                                            const __bf16* __restrict__ Bk,
                                                            __bf16* __restrict__ Ck,
                                                            const __bf16* __restrict__ Bv,
                                                            __bf16* __restrict__ Cv,
                                                            int M, int K,
                                                            const float* __restrict__ cosT,
                                                            const float* __restrict__ sinT) {
  extern __shared__ __bf16 smem[];
  const int id = blockIdx.x;
  if (id < 512) {
    const int gx = 16, wg = id, qq = 512 >> 3;
    const int id2 = (wg & 7) * qq + (wg >> 3);
    const int m0 = (id2 / gx) * 256, n0 = (id2 % gx) * 256;
    gemm_body<__bf16, 1>(A, Bq, Cq, M, 4096, K, cosT, sinT, 16, smem, m0, n0);
  } else if (id < 768) {
    const int gx = 8, wg = id - 512, qq = 256 >> 3;
    const int id2 = (wg & 7) * qq + (wg >> 3);
    const int m0 = (id2 / gx) * 256, n0 = (id2 % gx) * 256;
    gemm_body<__bf16, 1>(A, Bk, Ck, M, 2048, K, cosT, sinT, 8, smem, m0, n0);
  } else {
    const int gx = 8, wg = id - 768, qq = 256 >> 3;
    const int id2 = (wg & 7) * qq + (wg >> 3);
    const int m0 = (id2 / gx) * 256, n0 = (id2 % gx) * 256;
    gemm_body<__bf16, 2>(A, Bv, Cv, M, 2048, K, nullptr, nullptr, 8, smem, m0, n0);
  }
}

// ---------------- feature map (merged q+k: grid (32, 64); y>=32 = k path) -------------
__global__ __launch_bounds__(256) void fm_kernel(const __bf16* __restrict__ ropq,
                                                 const __bf16* __restrict__ ropk,
                                                 const float* __restrict__ fmq,
                                                 const float* __restrict__ fmk,
                                                 __bf16* __restrict__ outq,
                                                 __bf16* __restrict__ outk) {
  __shared__ __bf16 fmT[64][256];  // [f][d] swizzled: group' = (d>>3) ^ (f&7)
  const int half = blockIdx.y >> 5;
  const __bf16* rope = half ? ropk : ropq;
  const float* fm = half ? fmk : fmq;
  __bf16* out = half ? outk : outq;
  const int srcH = half ? 8 : 16;
  const float scale = half ? 1.0f : 0.08838834764831845f;

  int bh = blockIdx.y & 31;
  int h = bh & 15, b = bh >> 4;
  int s0 = blockIdx.x * 128;
  int tid = threadIdx.x, lane = tid & 63, wid = tid >> 6, hi = lane >> 4, lo = lane & 15;

  const float* fmh = fm + (size_t)h * 256 * 64;
  for (int i = tid; i < 256 * 64; i += 256) {
    int d = i >> 6, f = i & 63;
    fmT[f][(((d >> 3) ^ (f & 7)) << 3) | (d & 7)] = (__bf16)fmh[i];
  }
  __syncthreads();

  int srch = (srcH == 16) ? h : (h >> 1);
  const __bf16* abase = rope + ((size_t)(b * srcH + srch) * 4096 + s0 + 32 * wid) * 256;
  f32x4 acc[2][4] = {};
  for (int kk = 0; kk < 256; kk += 32) {
    bf16x8 a[2], bf[4];
    #pragma unroll
    for (int mt = 0; mt < 2; ++mt)
      a[mt] = *(const bf16x8*)(abase + (size_t)(16 * mt + lo) * 256 + kk + 8 * hi);
    const int G = (kk >> 3) + hi;
    #pragma unroll
    for (int nt = 0; nt < 4; ++nt) {
      int f = 16 * nt + lo;
      bf[nt] = *(const bf16x8*)&fmT[f][(G ^ (f & 7)) << 3];
    }
    #pragma unroll
    for (int mt = 0; mt < 2; ++mt)
      #pragma unroll
      for (int nt = 0; nt < 4; ++nt)
        acc[mt][nt] = MFMA16(a[mt], bf[nt], acc[mt][nt]);
  }

  size_t obase = ((size_t)(b * 16 + h) * 4096 + s0 + 32 * wid);
  #pragma unroll
  for (int mt = 0; mt < 2; ++mt) {
    #pragma unroll
    for (int r = 0; r < 4; ++r) {
      float z0 = acc[mt][0][r], z1 = acc[mt][1][r], z2 = acc[mt][2][r], z3 = acc[mt][3][r];
      float mx = fmaxf(fmaxf(z0, z1), fmaxf(z2, z3));
      float mn = fminf(fminf(z0, z1), fminf(z2, z3));
      #pragma unroll
      for (int off = 1; off < 16; off <<= 1) {
        mx = fmaxf(mx, __shfl_xor(mx, off));
        mn = fminf(mn, __shfl_xor(mn, off));
      }
      float ep0 = __expf(z0 - mx), ep1 = __expf(z1 - mx), ep2 = __expf(z2 - mx), ep3 = __expf(z3 - mx);
      float en0 = __expf(mn - z0), en1 = __expf(mn - z1), en2 = __expf(mn - z2), en3 = __expf(mn - z3);
      float sp = ep0 + ep1 + ep2 + ep3, sn = en0 + en1 + en2 + en3;
      #pragma unroll
      for (int off = 1; off < 16; off <<= 1) {
        sp += __shfl_xor(sp, off);
        sn += __shfl_xor(sn, off);
      }
      float rp = scale / sp, rn = scale / sn;
      int row = 16 * mt + 4 * hi + r;
      __bf16* op = out + (obase + row) * 128;
      op[0  + lo] = (__bf16)(ep0 * rp);  op[16 + lo] = (__bf16)(ep1 * rp);
      op[32 + lo] = (__bf16)(ep2 * rp);  op[48 + lo] = (__bf16)(ep3 * rp);
      op[64 + lo] = (__bf16)(en0 * rn);  op[80 + lo] = (__bf16)(en1 * rn);
      op[96 + lo] = (__bf16)(en2 * rn);  op[112 + lo] = (__bf16)(en3 * rn);
    }
  }
}

// ---------------- chunked linear attention (software-pipelined; best measured) ----------
// XCD swizzle (R7): dv-siblings share an XCD -> q/k head-slices L2-local.
// Pipeline (R8): double-buffered K/V, prefetch n+1 at top of n, light syncs.
__global__ __launch_bounds__(256) void attn_kernel(const __bf16* __restrict__ qf,
                                                   const __bf16* __restrict__ kf,
                                                   const __bf16* __restrict__ vp,
                                                   __bf16* __restrict__ o) {
  __shared__ __bf16 k_s[2][64][128];
  __shared__ __bf16 vT_s[2][32][64];
  __shared__ __bf16 sc_s[64][64];
  __shared__ __bf16 STb[32][128];

  int bid = blockIdx.x;
  int g   = ((bid >> 6) << 3) | (bid & 7);   // 0..31 = b*16 + h
  int dvb = (bid >> 3) & 7;
  int h = g & 15, b = g >> 4;
  int dv0 = dvb * 32;
  int tid = threadIdx.x, lane = tid & 63, wid = tid >> 6, hi = lane >> 4, lo = lane & 15;

  const __bf16* qh = qf + ((size_t)(b * 16 + h)) * 4096 * 128;
  const __bf16* kh = kf + ((size_t)(b * 16 + h)) * 4096 * 128;
  const __bf16* vh = vp + ((size_t)(b * 8 + (h >> 1))) * 4096 * 256 + dv0;
  __bf16* oh = o + ((size_t)b * 4096) * 4096 + h * 256 + dv0;

  {
    unsigned int* z = (unsigned int*)&STb[0][0];
    for (int i = tid; i < 2048; i += 256) z[i] = 0u;
  }
  f32x4 st[2][2] = {};

  const int vc = tid >> 2, vd8 = (tid & 3) * 8;
  bf16x8 aqN[4], aqC[4], vvN;

  // ---- prologue: K(0)->buf0, V(0)->reg, q(0)->reg; vT_s[0] write waits vv(0)
  // (FIFO => K(0) drained per-wave); lgkm(0)+barrier -> cross-wave visible.
  #pragma unroll
  for (int i = 0; i < 4; ++i) {
    int rb = (wid * 4 + i) * 4;
    int r = rb + (lane >> 4);
    int Glog = (lane & 15) ^ (r & 7);
    async_copy16(&k_s[0][rb][0], kh + (size_t)r * 128 + Glog * 8);
  }
  __builtin_amdgcn_sched_barrier(0);
  vvN = *(const bf16x8*)(vh + (size_t)vc * 256 + vd8);
  __builtin_amdgcn_sched_barrier(0);
  #pragma unroll
  for (int kq = 0; kq < 4; ++kq)
    aqN[kq] = *(const bf16x8*)(qh + (size_t)(16 * wid + lo) * 128 + 32 * kq + 8 * hi);
  __builtin_amdgcn_sched_barrier(0);
  #pragma unroll
  for (int j = 0; j < 8; ++j) {
    int dv = vd8 + j;
    vT_s[0][dv][(((vc >> 3) ^ (dv & 7)) << 3) | (vc & 7)] = vvN[j];
  }
  LGKM(0);
  BARRIER;

  for (int n = 0; n < 64; ++n) {
    const int buf = n & 1;
    const int s0 = n * 64;

    // consume q(n) (compiler waits the n-issued loads here), then prefetch n+1
    #pragma unroll
    for (int kq = 0; kq < 4; ++kq) aqC[kq] = aqN[kq];

    if (n < 63) {
      const int s1 = s0 + 64;
      #pragma unroll
      for (int i = 0; i < 4; ++i) {
        int rb = (wid * 4 + i) * 4;
        int r = rb + (lane >> 4);
        int Glog = (lane & 15) ^ (r & 7);
        async_copy16(&k_s[buf ^ 1][rb][0], kh + (size_t)(s1 + r) * 128 + Glog * 8);
      }
      __builtin_amdgcn_sched_barrier(0);
      vvN = *(const bf16x8*)(vh + (size_t)(s1 + vc) * 256 + vd8);
      __builtin_amdgcn_sched_barrier(0);
      #pragma unroll
      for (int kq = 0; kq < 4; ++kq)
        aqN[kq] = *(const bf16x8*)(qh + (size_t)(s1 + 16 * wid + lo) * 128 + 32 * kq + 8 * hi);
      __builtin_amdgcn_sched_barrier(0);
    }

    // ---- compute on buf: inter (q @ STb) + scores (q @ k)
    f32x4 acc_o[2] = {}, sacc[4] = {};
    #pragma unroll
    for (int nt = 0; nt < 2; ++nt)
      #pragma unroll
      for (int kq = 0; kq < 4; ++kq) {
        int rr = 16 * nt + lo, G = 4 * kq + hi;
        bf16x8 bf = *(const bf16x8*)&STb[rr][(G ^ (rr & 7)) << 3];
        acc_o[nt] = MFMA16(aqC[kq], bf, acc_o[nt]);
      }
    #pragma unroll
    for (int nt = 0; nt < 4; ++nt)
      #pragma unroll
      for (int kq = 0; kq < 4; ++kq) {
        int rr = 16 * nt + lo, G = 4 * kq + hi;
        bf16x8 bf = *(const bf16x8*)&k_s[buf][rr][(G ^ (rr & 7)) << 3];
        sacc[nt] = MFMA16(aqC[kq], bf, sacc[nt]);
      }
    // causal mask -> sc_s (wave-private 16-row band; intra-wave fence suffices)
    #pragma unroll
    for (int nt = 0; nt < 4; ++nt)
      #pragma unroll
      for (int r = 0; r < 4; ++r) {
        int c = 16 * wid + 4 * hi + r;
        int cp = 16 * nt + lo;
        float v = (cp <= c) ? sacc[nt][r] : 0.0f;
        sc_s[c][(((cp >> 3) ^ (c & 7)) << 3) | (cp & 7)] = (__bf16)v;
      }
    asm volatile("" ::: "memory");
    // intra: sc @ vT
    #pragma unroll
    for (int nt = 0; nt < 2; ++nt)
      #pragma unroll
      for (int kq = 0; kq < 2; ++kq) {
        int rA = 16 * wid + lo, GA = 4 * kq + hi;
        bf16x8 af = *(const bf16x8*)&sc_s[rA][(GA ^ (rA & 7)) << 3];
        int rB = 16 * nt + lo;
        bf16x8 bf = *(const bf16x8*)&vT_s[buf][rB][(GA ^ (rB & 7)) << 3];
        acc_o[nt] = MFMA16(af, bf, acc_o[nt]);
      }
    #pragma unroll
    for (int nt = 0; nt < 2; ++nt)
      #pragma unroll
      for (int r = 0; r < 4; ++r) {
        int c = 16 * wid + 4 * hi + r;
        oh[(size_t)(s0 + c) * 4096 + 16 * nt + lo] = (__bf16)acc_o[nt][r];
      }

    if (n == 63) break;   // ST update is dead on the last chunk

    BARRIER;  // mid: raw barrier (all pre-barrier LDS reads register-consumed)

    // ---- ST update: st += v^T @ k  (bu rebuilt from k_s[buf])
    bf16x8 bu[2][2];
    #pragma unroll
    for (int q = 0; q < 2; ++q) {
      int dk = 16 * (2 * wid + q) + lo;
      #pragma unroll
      for (int kq = 0; kq < 2; ++kq) {
        bf16x8 tmp;
        #pragma unroll
        for (int j = 0; j < 8; ++j) {
          int c = 32 * kq + 8 * hi + j;
          tmp[j] = k_s[buf][c][(((dk >> 3) ^ (c & 7)) << 3) | (dk & 7)];
        }
        bu[q][kq] = tmp;
      }
    }
    #pragma unroll
    for (int mt = 0; mt < 2; ++mt)
      #pragma unroll
      for (int kq = 0; kq < 2; ++kq) {
        int rA = 16 * mt + lo, GA = 4 * kq + hi;
        bf16x8 av = *(const bf16x8*)&vT_s[buf][rA][(GA ^ (rA & 7)) << 3];
        #pragma unroll
        for (int q = 0; q < 2; ++q)
          st[mt][q] = MFMA16(av, bu[q][kq], st[mt][q]);
      }
    #pragma unroll
    for (int mt = 0; mt < 2; ++mt)
      #pragma unroll
      for (int q = 0; q < 2; ++q) {
        int dk = 16 * (2 * wid + q) + lo;
        #pragma unroll
        for (int r = 0; r < 4; ++r) {
          int dvr = 16 * mt + 4 * hi + r;
          STb[dvr][(((dk >> 3) ^ (dvr & 7)) << 3) | (dk & 7)] = (__bf16)st[mt][q][r];
        }
      }
    // vT_s[buf^1] <- vv(n+1): compiler waits vv(n+1) => K(n+1) (older) drained
    #pragma unroll
    for (int j = 0; j < 8; ++j) {
      int dv = vd8 + j;
      vT_s[buf ^ 1][dv][(((vc >> 3) ^ (dv & 7)) << 3) | (vc & 7)] = vvN[j];
    }
    LGKM(0);   // ds_writes (STb, vT_s) visible cross-wave after barrier
    BARRIER;
  }
}

// ---------------- launch ----------------
extern "C" void kernel_launch(void* const* d_in, const int* in_sizes, int n_in,
                              void* d_out, int out_size, void* d_ws, size_t ws_size,
                              hipStream_t stream) {
  (void)in_sizes; (void)n_in; (void)out_size; (void)ws_size;
  const float* hs   = (const float*)d_in[0];
  const float* cosT = (const float*)d_in[1];
  const float* sinT = (const float*)d_in[2];
  const float* Wq   = (const float*)d_in[3];
  const float* Wk   = (const float*)d_in[4];
  const float* Wv   = (const float*)d_in[5];
  const float* Wo   = (const float*)d_in[6];
  const float* fmq  = (const float*)d_in[7];
  const float* fmk  = (const float*)d_in[8];
  float* out = (float*)d_out;
  char* ws = (char*)d_ws;

  hipFuncSetAttribute((const void*)gemm256_kernel<float, 0>,
                      hipFuncAttributeMaxDynamicSharedMemorySize, 131072);
  hipFuncSetAttribute((const void*)gemm256qkv_kernel,
                      hipFuncAttributeMaxDynamicSharedMemorySize, 131072);

  const size_t MB = 1024ull * 1024ull;
  __bf16* Xb   = (__bf16*)(ws + 0);
  __bf16* qfb  = (__bf16*)(ws + 0);
  __bf16* kfb  = (__bf16*)(ws + 34 * MB);
  __bf16* Wqt  = (__bf16*)(ws + 70 * MB);
  __bf16* ob   = (__bf16*)(ws + 70 * MB);
  __bf16* Wkt  = (__bf16*)(ws + 104 * MB);
  __bf16* Wvt  = (__bf16*)(ws + 119 * MB);
  __bf16* Wot  = (__bf16*)(ws + 140 * MB);
  __bf16* ropq = (__bf16*)(ws + 170 * MB);
  __bf16* ropk = (__bf16*)(ws + 238 * MB);
  __bf16* vpb  = (__bf16*)(ws + 272 * MB);

  prologue_kernel<<<71680, 256, 0, stream>>>(hs, Xb, Wq, Wqt, Wk, Wkt, Wv, Wvt, Wo, Wot);

  gemm256qkv_kernel<<<1024, 512, 131072, stream>>>(
      Xb, Wqt, ropq, Wkt, ropk, Wvt, vpb, 8192, 3584, cosT, sinT);

  fm_kernel<<<dim3(32, 64), 256, 0, stream>>>(ropq, ropk, fmq, fmk, qfb, kfb);

  attn_kernel<<<256, 256, 0, stream>>>(qfb, kfb, vpb, ob);

  gemm256_kernel<float, 0><<<dim3(14, 32), 512, 131072, stream>>>(
      ob, Wot, out, 8192, 3584, 4096, nullptr, nullptr, 0);
}